// Round 7
// baseline (189.688 us; speedup 1.0000x reference)
//
#include <hip/hip_runtime.h>
#include <hip/hip_bf16.h>

// Problem: B=2, S=2048, D=768, H=12, HD=64. fp32 in/out, bf16 MFMA inside.
// r28 = r26 attn (measured best: 55.2us, key-split, V in LDS) + COMBINE
// FOLDED INTO GEMM2: gemm2_fused stages A by reading the two f32 partials,
// computing (p0+p1)*1/(l0+l1) (head = kk>>6 const per BK=32 step; per-block
// linv[64][13] LDS table), cvt->bf16, ds_write. B stays glds16. Op-for-op
// identical math to the old combine kernel -> bit-identical output. Saves
// the combine dispatch (~6-8us) + the o_x16 bf16 round-trip (12.6MB).
// o_p0 moved off d_out into ws (d_out aliasing would race GEMM2 epilogue).
// Win ledger: r4 LDS staging+dbuf, r5 xor-swizzle, r10 coalesced repack,
// r15 GEMM2 64x64, r18 GEMM1 128x96, r22 swapped-QK^T in-register P,
// r24 glds16 pre-swizzled staging + l-on-MFMA, r26 key-split (attn 55.2).
// Failure ledger (do not revisit): r7 mfma16, r8 wave-split, r11 32x32 MFMA,
// r12 BK=64, r9/r13/r14 math micro-opts, r16 GEMM1 64x128, r20 GEMM2 dbuf,
// r23 2-wave/32q blocks, r25 V-direct-global mid-iter (vmcnt drained K
// prefetch), r27 V-reg-prefetch post-PV (V latency landed on barrier,
// 55.2->62.4us).
#define B_ 2
#define S_ 2048
#define D_ 768
#define H_ 12
#define HD_ 64
#define EXP2C_ 0.1803368801111244f  // SCALE * log2(e), folded into Q

typedef __attribute__((ext_vector_type(8))) short bf16x8;
typedef __attribute__((ext_vector_type(8))) unsigned short u16x8;
typedef __attribute__((ext_vector_type(4))) float f32x4;
typedef __attribute__((ext_vector_type(4))) unsigned int u32x4;

static __device__ __forceinline__ unsigned short f2bf(float x) {
    union { float f; unsigned u; } v; v.f = x;
    unsigned r = (v.u + 0x7FFFu + ((v.u >> 16) & 1u)) >> 16;  // RNE
    return (unsigned short)r;
}
static __device__ __forceinline__ float bf2f(unsigned short h) {
    union { unsigned u; float f; } v; v.u = ((unsigned)h) << 16;
    return v.f;
}
static __device__ __forceinline__ float fexp2(float x) { return __builtin_exp2f(x); }

// packed f32x2 -> bf16x2 (v_cvt_pk_bf16_f32) as raw u32; low 16 = first arg
static __device__ __forceinline__ unsigned pk_bf16(float a, float b) {
    __hip_bfloat162 pk = __float22bfloat162_rn(make_float2(a, b));
    union { __hip_bfloat162 h; unsigned u; } v; v.h = pk;
    return v.u;
}

static __device__ __forceinline__ f32x4 mfma32(bf16x8 a, bf16x8 b, f32x4 c) {
    return __builtin_amdgcn_mfma_f32_16x16x32_bf16(a, b, c, 0, 0, 0);
}

// async global->LDS, 16B/lane; LDS dest = wave-uniform base + lane*16 (m97)
typedef __attribute__((address_space(3))) unsigned int lds_u32;
typedef __attribute__((address_space(1))) const unsigned int glb_u32;
static __device__ __forceinline__ void glds16(const unsigned short* g, unsigned short* l) {
    __builtin_amdgcn_global_load_lds((glb_u32*)g, (lds_u32*)l, 16, 0, 0);
}

// ---------------------------------------------------------------------------
// Merged prep: conv x->bf16 | transpose w_qkv | transpose w_proj.
// ---------------------------------------------------------------------------
#define PREP_CONV_ 1536   // 4096*768/(256*8)
#define PREP_TQKV_ 1728   // (2304/32)*(768/32)
#define PREP_TPRJ_ 576    // (768/32)*(768/32)
__global__ __launch_bounds__(256) void prep_kernel(
    const float* __restrict__ x,      unsigned short* __restrict__ x16,
    const float* __restrict__ w_qkv,  unsigned short* __restrict__ wqkvT,
    const float* __restrict__ w_proj, unsigned short* __restrict__ wprojT)
{
    __shared__ float tile[32][33];
    const int bid = blockIdx.x, t = threadIdx.x;
    if (bid < PREP_CONV_) {
        const int i = (bid * 256 + t) * 8;
        float4 a0 = *(const float4*)(x + i);
        float4 a1 = *(const float4*)(x + i + 4);
        u16x8 s;
        s[0] = f2bf(a0.x); s[1] = f2bf(a0.y); s[2] = f2bf(a0.z); s[3] = f2bf(a0.w);
        s[4] = f2bf(a1.x); s[5] = f2bf(a1.y); s[6] = f2bf(a1.z); s[7] = f2bf(a1.w);
        *(u16x8*)(x16 + i) = s;
        return;
    }
    const float* w; unsigned short* wT; int N, bb;
    if (bid < PREP_CONV_ + PREP_TQKV_) { w = w_qkv; wT = wqkvT; N = 3 * D_; bb = bid - PREP_CONV_; }
    else                               { w = w_proj; wT = wprojT; N = D_;   bb = bid - PREP_CONV_ - PREP_TQKV_; }
    const int K = D_;
    const int nt = N / 32;
    const int n0 = (bb % nt) * 32, k0 = (bb / nt) * 32;
    const int tx = t & 31, ty = t >> 5;
#pragma unroll
    for (int i = 0; i < 4; i++)
        tile[ty + i * 8][tx] = w[(size_t)(k0 + ty + i * 8) * N + n0 + tx];
    __syncthreads();
#pragma unroll
    for (int i = 0; i < 4; i++)
        wT[(size_t)(n0 + ty + i * 8) * K + k0 + tx] = f2bf(tile[tx][ty + i * 8]);
}

// ---------------------------------------------------------------------------
// Pure-bf16 GEMM + bias: C[M][N] = A[M][K] . Bt[N][K]^T + bias[N]
// BMxBN tile, BK=32, 4 waves (each (BM/2)x(BN/2) quadrant), glds16 staging.
// Used for GEMM1 only (128x96, 768 blocks = 3/CU, r18 win).
// ---------------------------------------------------------------------------
template <int BM, int BN, bool OUT_F32>
__global__ __launch_bounds__(256) void gemm_bt_kernel(
    const unsigned short* __restrict__ A,
    const unsigned short* __restrict__ Bt,
    const float* __restrict__ bias,
    void* __restrict__ Cp,
    int M, int N, int K)
{
    __shared__ __align__(16) unsigned short As[BM][32];
    __shared__ __align__(16) unsigned short Bs[BN][32];
    constexpr int MI = BM / 32, NJ = BN / 32;   // frags per wave quadrant
    constexpr int ACH = BM * 4, BCH = BN * 4;   // 16B chunks per tile

    const int t = threadIdx.x;
    const int w = t >> 6, lane = t & 63, quad = lane >> 4, l16 = lane & 15;
    const int n0 = blockIdx.x * BN, m0 = blockIdx.y * BM;
    const int mw = (w & 1) * (BM / 2), nw = (w >> 1) * (BN / 2);

    const f32x4 z = {0.f, 0.f, 0.f, 0.f};
    f32x4 acc[MI][NJ];
#pragma unroll
    for (int i = 0; i < MI; i++)
#pragma unroll
        for (int j = 0; j < NJ; j++) acc[i][j] = z;

    for (int kk = 0; kk < K; kk += 32) {
#pragma unroll
        for (int it = 0; it < (ACH + 255) / 256; it++) {
            const int c = t + it * 256;
            if (ACH % 256 == 0 || c < ACH) {
                const int row = c >> 2, c8 = (c & 3) << 3;
                glds16(A + (size_t)(m0 + row) * K + kk + c8, &As[0][0] + c * 8);
            }
        }
#pragma unroll
        for (int it = 0; it < (BCH + 255) / 256; it++) {
            const int c = t + it * 256;
            if (BCH % 256 == 0 || c < BCH) {
                const int row = c >> 2, c8 = (c & 3) << 3;
                glds16(Bt + (size_t)(n0 + row) * K + kk + c8, &Bs[0][0] + c * 8);
            }
        }
        __syncthreads();

        bf16x8 a[MI], b[NJ];
#pragma unroll
        for (int i = 0; i < MI; i++)
            a[i] = *(const bf16x8*)(&As[mw + i * 16 + l16][quad * 8]);
#pragma unroll
        for (int j = 0; j < NJ; j++)
            b[j] = *(const bf16x8*)(&Bs[nw + j * 16 + l16][quad * 8]);
#pragma unroll
        for (int i = 0; i < MI; i++)
#pragma unroll
            for (int j = 0; j < NJ; j++)
                acc[i][j] = mfma32(a[i], b[j], acc[i][j]);
        __syncthreads();
    }

#pragma unroll
    for (int j = 0; j < NJ; j++) {
        const int col = n0 + nw + j * 16 + l16;
        const float bv = bias[col];
#pragma unroll
        for (int i = 0; i < MI; i++) {
#pragma unroll
            for (int r = 0; r < 4; r++) {
                const int row = m0 + mw + i * 16 + quad * 4 + r;
                const float v = acc[i][j][r] + bv;
                if (OUT_F32) ((float*)Cp)[(size_t)row * N + col] = v;
                else         ((unsigned short*)Cp)[(size_t)row * N + col] = f2bf(v);
            }
        }
    }
}

// ---------------------------------------------------------------------------
// Repack V (r10, measured good): LDS-tiled transpose, coalesced both sides.
// ---------------------------------------------------------------------------
__global__ __launch_bounds__(256) void repack_v_kernel(
    const unsigned short* __restrict__ qkv,
    unsigned short* __restrict__ vt)
{
    __shared__ unsigned short T[64][65];
    const int t = threadIdx.x;
    const int bh = blockIdx.x, st = blockIdx.y;
    const int b = bh / H_, h = bh % H_;
    const unsigned short* src =
        qkv + (size_t)(b * S_ + st * 64) * (3 * D_) + 2 * D_ + h * HD_;

#pragma unroll
    for (int it = 0; it < 2; it++) {
        const int c = t + it * 256, sr = c >> 3, g = c & 7;
        u16x8 v = *(const u16x8*)(src + (size_t)sr * (3 * D_) + g * 8);
#pragma unroll
        for (int j = 0; j < 8; j++) T[sr][g * 8 + j] = v[j];
    }
    __syncthreads();
#pragma unroll
    for (int it = 0; it < 2; it++) {
        const int c = t + it * 256, hd = c >> 3, g = c & 7;
        u16x8 v;
#pragma unroll
        for (int j = 0; j < 8; j++) v[j] = T[g * 8 + j][hd];
        *(u16x8*)(vt + (size_t)(bh * HD_ + hd) * S_ + st * 64 + g * 8) = v;
    }
}

// ---------------------------------------------------------------------------
// Flash attention — r26 verbatim (measured 55.2us): key-split over
// blockIdx.z (2 halves of 1024 keys); K and V glds16-staged into swizzled
// LDS with dbuf; emits UNNORMALIZED f32 partial o and per-(row,head) l.
//
// Key-row permutation (r22, verified): A-frag row l16 of tile-slice nt reads
// Ks row rowp = (nt>>1)*32 + (l16>>2)*8 + (nt&1)*4 + (l16&3) =>
// s_acc[nt][r] = S[key=(nt>>1)*32+quad*8+(nt&1)*4+r][q=l16]; packed pa0/pa1
// are exactly the PV A-frags (k=quad*8+j over keys 0..31 / 32..63).
// Ks swizzle sK(row) = (row&3)|((row>>3&1)<<2); Vs swizzle g^(row&7).
// glds16 staging with pre-swizzled global source (linear LDS dest).
// l-ones: mfma(pa, ones) -> C rows match o_acc rows; l[r] lane-local.
// ---------------------------------------------------------------------------
__global__ __launch_bounds__(256) void attn_kernel(
    const unsigned short* __restrict__ qkv,  // [B*S][3*D] bf16
    const unsigned short* __restrict__ vt,   // [B*H][HD][S] bf16
    float* __restrict__ o_p0,                // [B*S][D] f32 partial, half 0
    float* __restrict__ o_p1,                // [B*S][D] f32 partial, half 1
    float* __restrict__ l_p)                 // [2][B*S][H] f32
{
    __shared__ __align__(16) unsigned short Ks[2][64][64];   // [key][hd], sK swizzle
    __shared__ __align__(16) unsigned short Vs[2][64][64];   // [hd][key], g^(row&7)

    const int t = threadIdx.x;
    const int w = t >> 6, lane = t & 63, quad = lane >> 4, l16 = lane & 15;
    const int h8 = l16 & 7;
    const int qt = blockIdx.x, bh = blockIdx.y, ks = blockIdx.z;
    const int b = bh / H_, h = bh % H_;
    const int ld = 3 * D_;  // 2304

    // Q B-frags (n=l16 -> q row, k=quad*8+j), prescaled by SCALE*log2e
    const unsigned short* qbase =
        qkv + (size_t)(b * S_ + qt * 64 + 16 * w + l16) * ld + h * HD_;
    u16x8 qr0 = *(const u16x8*)(qbase + quad * 8);
    u16x8 qr1 = *(const u16x8*)(qbase + 32 + quad * 8);
    bf16x8 qf0, qf1;
#pragma unroll
    for (int j = 0; j < 8; j++) {
        qf0[j] = (short)f2bf(bf2f(qr0[j]) * EXP2C_);
        qf1[j] = (short)f2bf(bf2f(qr1[j]) * EXP2C_);
    }

    bf16x8 ones;
#pragma unroll
    for (int j = 0; j < 8; j++) ones[j] = (short)0x3F80;  // bf16 1.0

    // key-half base offsets (1024 keys per half)
    const unsigned short* kbase =
        qkv + (size_t)(b * S_ + ks * 1024) * ld + D_ + h * HD_;
    const unsigned short* vbase = vt + (size_t)bh * HD_ * S_;

    // per-lane staging source addresses (pre-swizzled global groups)
    const int c0 = t, c1 = t + 256;
    const int row0 = c0 >> 3, row1 = c1 >> 3;
    const int kg0 = (c0 & 7) ^ ((row0 & 3) | (((row0 >> 3) & 1) << 2));
    const int kg1 = (c1 & 7) ^ ((row1 & 3) | (((row1 >> 3) & 1) << 2));
    const int vg0 = (c0 & 7) ^ (row0 & 7);
    const int vg1 = (c1 & 7) ^ (row1 & 7);
    const unsigned short* kp0 = kbase + (size_t)row0 * ld + kg0 * 8;
    const unsigned short* kp1 = kbase + (size_t)row1 * ld + kg1 * 8;
    const unsigned short* vp0 = vbase + (size_t)row0 * S_ + ks * 1024 + vg0 * 8;
    const unsigned short* vp1 = vbase + (size_t)row1 * S_ + ks * 1024 + vg1 * 8;
    const size_t KSTEP = (size_t)64 * ld;  // elements per KV tile (K side)

    const f32x4 z = {0.f, 0.f, 0.f, 0.f};
    f32x4 o_acc[4] = {z, z, z, z};
    f32x4 l_acc = z;

    // prologue: stage tile 0 into buf 0
    glds16(kp0, &Ks[0][0][0] + c0 * 8);
    glds16(kp1, &Ks[0][0][0] + c1 * 8);
    glds16(vp0, &Vs[0][0][0] + c0 * 8);
    glds16(vp1, &Vs[0][0][0] + c1 * 8);
    kp0 += KSTEP; kp1 += KSTEP; vp0 += 64; vp1 += 64;
    __syncthreads();

    const int NT = 1024 / 64;  // 16 tiles per half
    for (int kt = 0; kt < NT; kt++) {
        const int buf = kt & 1;

        // prefetch tile kt+1 into buf^1 (async, drains at the barrier)
        if (kt + 1 < NT) {
            unsigned short* kd = &Ks[buf ^ 1][0][0];
            unsigned short* vd = &Vs[buf ^ 1][0][0];
            glds16(kp0, kd + c0 * 8);
            glds16(kp1, kd + c1 * 8);
            glds16(vp0, vd + c0 * 8);
            glds16(vp1, vd + c1 * 8);
            kp0 += KSTEP; kp1 += KSTEP; vp0 += 64; vp1 += 64;
        }

        // S^T = K . Q^T from LDS: s_acc[nt][r] = S[key=perm(nt,quad*4+r)][q=l16]
        f32x4 s_acc[4] = {z, z, z, z};
#pragma unroll
        for (int nt = 0; nt < 4; nt++) {
            const int rowp = ((nt >> 1) << 5) + ((l16 >> 2) << 3) + ((nt & 1) << 2) + (l16 & 3);
            const int skr = (rowp & 3) | (((rowp >> 3) & 1) << 2);
            const unsigned short* kr = &Ks[buf][rowp][0];
            bf16x8 k0 = *(const bf16x8*)(kr + (quad ^ skr) * 8);
            bf16x8 k1 = *(const bf16x8*)(kr + ((quad ^ skr) ^ 4) * 8);
            s_acc[nt] = mfma32(k0, qf0, s_acc[nt]);
            s_acc[nt] = mfma32(k1, qf1, s_acc[nt]);
        }

        // V-frag reads issued early; lgkm latency hides under exp2/pack
        bf16x8 vr0[4], vr1[4];
#pragma unroll
        for (int nt = 0; nt < 4; nt++) {
            const int row = nt * 16 + l16;
            vr0[nt] = *(const bf16x8*)(&Vs[buf][row][(quad ^ h8) * 8]);
            vr1[nt] = *(const bf16x8*)(&Vs[buf][row][((quad ^ h8) ^ 4) * 8]);
        }

        // p = exp2(s); pack to PV A-frags in registers
        f32x4 pr[4];
#pragma unroll
        for (int nt = 0; nt < 4; nt++) {
#pragma unroll
            for (int r = 0; r < 4; r++) pr[nt][r] = fexp2(s_acc[nt][r]);
        }
        union { u32x4 u; bf16x8 h; } ca, cb;
        ca.u[0] = pk_bf16(pr[0][0], pr[0][1]);
        ca.u[1] = pk_bf16(pr[0][2], pr[0][3]);
        ca.u[2] = pk_bf16(pr[1][0], pr[1][1]);
        ca.u[3] = pk_bf16(pr[1][2], pr[1][3]);
        cb.u[0] = pk_bf16(pr[2][0], pr[2][1]);
        cb.u[1] = pk_bf16(pr[2][2], pr[2][3]);
        cb.u[2] = pk_bf16(pr[3][0], pr[3][1]);
        cb.u[3] = pk_bf16(pr[3][2], pr[3][3]);
        const bf16x8 pa0 = ca.h, pa1 = cb.h;

        // l on the MFMA pipe: C rows match o_acc rows, dup over cols
        l_acc = mfma32(pa0, ones, l_acc);
        l_acc = mfma32(pa1, ones, l_acc);

        // O += P . V from LDS (register V frags)
#pragma unroll
        for (int nt = 0; nt < 4; nt++) {
            o_acc[nt] = mfma32(pa0, vr0[nt], o_acc[nt]);
            o_acc[nt] = mfma32(pa1, vr1[nt], o_acc[nt]);
        }

        __syncthreads();  // drains glds16 (vmcnt) -> buf^1 complete
    }

    // epilogue: write unnormalized f32 partials + l (lane-local, no shuffles)
    float* op = ks ? o_p1 : o_p0;
    float* lp2 = l_p + (size_t)ks * (B_ * S_ * H_);
#pragma unroll
    for (int r = 0; r < 4; r++) {
        const int row = b * S_ + qt * 64 + 16 * w + quad * 4 + r;
        float* ob = op + (size_t)row * D_ + h * HD_;
#pragma unroll
        for (int nt = 0; nt < 4; nt++)
            ob[nt * 16 + l16] = o_acc[nt][r];
        if (l16 == 0) lp2[(size_t)row * H_ + h] = l_acc[r];
    }
}

// ---------------------------------------------------------------------------
// GEMM2 fused with combine (r28): out[M][N] = A . wprojT^T + bias, where
// A[m][k] = (o_p0[m][k] + o_p1[m][k]) * 1/(l0[m][k>>6] + l1[m][k>>6]),
// computed during A-staging (f32 loads + VALU + cvt + ds_write_b128); B via
// glds16. Per-block linv[64][13] LDS table (pad 13 -> <=2-way, free).
// Math is op-for-op identical to the old combine kernel (same f2bf((a+b)*inv)).
// M=4096, N=768, K=768, BM=BN=64, BK=32; grid (12,64)=768 = 3/CU.
// ---------------------------------------------------------------------------
__global__ __launch_bounds__(256) void gemm2_fused_kernel(
    const float* __restrict__ o_p0,
    const float* __restrict__ o_p1,
    const float* __restrict__ l_p,
    const unsigned short* __restrict__ Bt,   // wprojT [768][768]
    const float* __restrict__ bias,
    float* __restrict__ out)
{
    __shared__ __align__(16) unsigned short As[64][32];
    __shared__ __align__(16) unsigned short Bs[64][32];
    __shared__ float linv[64 * 13];

    const int t = threadIdx.x;
    const int w = t >> 6, lane = t & 63, quad = lane >> 4, l16 = lane & 15;
    const int n0 = blockIdx.x * 64, m0 = blockIdx.y * 64;
    const int mw = (w & 1) * 32, nw = (w >> 1) * 32;

    // prologue: 1/(l0+l1) for rows m0..m0+63, heads 0..11
    for (int i = t; i < 64 * H_; i += 256) {
        const int row = i / H_, hh = i - row * H_;
        const float l0 = l_p[(size_t)(m0 + row) * H_ + hh];
        const float l1 = l_p[(size_t)(B_ * S_ * H_) + (size_t)(m0 + row) * H_ + hh];
        linv[row * 13 + hh] = 1.f / (l0 + l1);
    }

    const f32x4 z = {0.f, 0.f, 0.f, 0.f};
    f32x4 acc[2][2];
#pragma unroll
    for (int i = 0; i < 2; i++)
#pragma unroll
        for (int j = 0; j < 2; j++) acc[i][j] = z;

    // A-chunk mapping identical to glds16 path: chunk c=t -> row=t>>2,
    // col8=(t&3)*8; dest = &As[0][0] + t*8 (linear).
    const int arow = t >> 2, ac8 = (t & 3) << 3;
    const float* ap0 = o_p0 + (size_t)(m0 + arow) * D_ + ac8;
    const float* ap1 = o_p1 + (size_t)(m0 + arow) * D_ + ac8;
    const unsigned short* bp = Bt + (size_t)(n0 + arow) * D_ + ac8;

    __syncthreads();  // linv ready

    for (int kk = 0; kk < D_; kk += 32) {
        // A partial loads (issued first so their waitcnt leaves B in flight)
        const float4 a0 = *(const float4*)(ap0 + kk);
        const float4 a1 = *(const float4*)(ap0 + kk + 4);
        const float4 b0 = *(const float4*)(ap1 + kk);
        const float4 b1 = *(const float4*)(ap1 + kk + 4);
        // B async staging
        glds16(bp + kk, &Bs[0][0] + t * 8);
        // combine + normalize + cvt -> staged A tile
        const float inv = linv[arow * 13 + (kk >> 6)];
        u16x8 s;
        s[0] = f2bf((a0.x + b0.x) * inv); s[1] = f2bf((a0.y + b0.y) * inv);
        s[2] = f2bf((a0.z + b0.z) * inv); s[3] = f2bf((a0.w + b0.w) * inv);
        s[4] = f2bf((a1.x + b1.x) * inv); s[5] = f2bf((a1.y + b1.y) * inv);
        s[6] = f2bf((a1.z + b1.z) * inv); s[7] = f2bf((a1.w + b1.w) * inv);
        *(u16x8*)(&As[0][0] + t * 8) = s;
        __syncthreads();

        bf16x8 a[2], b[2];
#pragma unroll
        for (int i = 0; i < 2; i++)
            a[i] = *(const bf16x8*)(&As[mw + i * 16 + l16][quad * 8]);
#pragma unroll
        for (int j = 0; j < 2; j++)
            b[j] = *(const bf16x8*)(&Bs[nw + j * 16 + l16][quad * 8]);
#pragma unroll
        for (int i = 0; i < 2; i++)
#pragma unroll
            for (int j = 0; j < 2; j++)
                acc[i][j] = mfma32(a[i], b[j], acc[i][j]);
        __syncthreads();
    }

#pragma unroll
    for (int j = 0; j < 2; j++) {
        const int col = n0 + nw + j * 16 + l16;
        const float bv = bias[col];
#pragma unroll
        for (int i = 0; i < 2; i++) {
#pragma unroll
            for (int r = 0; r < 4; r++) {
                const int row = m0 + mw + i * 16 + quad * 4 + r;
                out[(size_t)row * D_ + col] = acc[i][j][r] + bv;
            }
        }
    }
}

// ---------------------------------------------------------------------------
extern "C" void kernel_launch(void* const* d_in, const int* in_sizes, int n_in,
                              void* d_out, int out_size, void* d_ws, size_t ws_size,
                              hipStream_t stream) {
    const float* x      = (const float*)d_in[0];  // [4096][768]
    const float* w_qkv  = (const float*)d_in[1];  // [768][2304]
    const float* b_qkv  = (const float*)d_in[2];  // [2304]
    const float* w_proj = (const float*)d_in[3];  // [768][768]
    const float* b_proj = (const float*)d_in[4];  // [768]
    float* out = (float*)d_out;                   // [4096][768]

    // ws carve. x16 feeds GEMM1 only now (attn emits f32 partials).
    // o_p0 lives in ws (NOT d_out: gemm2_fused reads it while writing out).
    unsigned short* qkv    = (unsigned short*)d_ws;                     // 9,437,184
    unsigned short* vtb    = qkv    + (size_t)(B_ * S_) * (3 * D_);     // 3,145,728
    unsigned short* x16    = vtb    + (size_t)(B_ * H_) * HD_ * S_;     // 3,145,728
    unsigned short* wqkvT  = x16    + (size_t)(B_ * S_) * D_;           // 1,769,472
    unsigned short* wprojT = wqkvT  + (size_t)D_ * (3 * D_);            //   589,824
    float* o_p1 = (float*)(wprojT + (size_t)D_ * D_);                   // 3,145,728 f32
    float* l_p  = o_p1 + (size_t)(B_ * S_) * D_;                        // 2*4096*12 f32
    float* o_p0 = l_p + (size_t)2 * B_ * S_ * H_;                       // 3,145,728 f32

    dim3 blk(256);
    prep_kernel<<<dim3(PREP_CONV_ + PREP_TQKV_ + PREP_TPRJ_), blk, 0, stream>>>(
        x, x16, w_qkv, wqkvT, w_proj, wprojT);
    gemm_bt_kernel<128, 96, false><<<dim3((3 * D_) / 96, (B_ * S_) / 128), blk, 0, stream>>>(
        x16, wqkvT, b_qkv, qkv, B_ * S_, 3 * D_, D_);
    repack_v_kernel<<<dim3(B_ * H_, S_ / 64), blk, 0, stream>>>(qkv, vtb);
    attn_kernel<<<dim3(S_ / 64, B_ * H_, 2), blk, 0, stream>>>(qkv, vtb, o_p0, o_p1, l_p);
    gemm2_fused_kernel<<<dim3(D_ / 64, (B_ * S_) / 64), blk, 0, stream>>>(
        o_p0, o_p1, l_p, wprojT, b_proj, out);
}

// Round 9
// 171.247 us; speedup vs baseline: 1.1077x; 1.1077x over previous
//
#include <hip/hip_runtime.h>
#include <hip/hip_bf16.h>

// Problem: B=2, S=2048, D=768, H=12, HD=64. fp32 in/out, bf16 MFMA inside.
// r30 = r26 pipeline (passing, attn 55.2us split-k + combine kernel) +
// (1) GEMM BK=64 + g^(row&7) XOR-swizzle on As/Bs (attn-proven Vs pattern:
//     row stride 128B, pre-swizzled glds16 source, linear LDS dest, read at
//     lg^(row&7) -> 2-way max = free). Kills the m98-signature 8-way frag
//     conflicts of the old [BM][32] layout AND halves K-iters 24->12
//     (half the barrier drains). GEMM1 LDS 28.7KB (3 blk/CU), GEMM2 16KB.
// (2) attn setprio(1/0) around QK and l+PV MFMA clusters (T5, m191: +4-7%
//     in multi-block unsynced regime = our 5 blk/CU split-k).
// Win ledger: r4 LDS staging+dbuf, r5 xor-swizzle, r10 coalesced repack,
// r15 GEMM2 64x64, r18 GEMM1 128x96, r22 swapped-QK^T in-register P,
// r24 glds16 pre-swizzled staging + l-on-MFMA, r26 key-split (attn 55.2).
// Failure ledger (do not revisit): r7 mfma16, r8 wave-split, r11 32x32 MFMA,
// r12 attn BK=64, r9/r13/r14 math micro-opts, r16 GEMM1 64x128, r20 GEMM2
// dbuf, r23 2-wave/32q blocks, r25 V-direct-global mid-iter, r27 V-reg
// prefetch post-PV, r28 gemm2-fused combine (A f32 re-read x12),
// r29 last-arriver cross-block combine (XCD non-coherent stale reads on
// graph replay -> tripwire FAIL; never exchange non-atomic data between
// blocks in-kernel).
#define B_ 2
#define S_ 2048
#define D_ 768
#define H_ 12
#define HD_ 64
#define EXP2C_ 0.1803368801111244f  // SCALE * log2(e), folded into Q

typedef __attribute__((ext_vector_type(8))) short bf16x8;
typedef __attribute__((ext_vector_type(8))) unsigned short u16x8;
typedef __attribute__((ext_vector_type(4))) float f32x4;
typedef __attribute__((ext_vector_type(4))) unsigned int u32x4;

static __device__ __forceinline__ unsigned short f2bf(float x) {
    union { float f; unsigned u; } v; v.f = x;
    unsigned r = (v.u + 0x7FFFu + ((v.u >> 16) & 1u)) >> 16;  // RNE
    return (unsigned short)r;
}
static __device__ __forceinline__ float bf2f(unsigned short h) {
    union { unsigned u; float f; } v; v.u = ((unsigned)h) << 16;
    return v.f;
}
static __device__ __forceinline__ float fexp2(float x) { return __builtin_exp2f(x); }

// packed f32x2 -> bf16x2 (v_cvt_pk_bf16_f32) as raw u32; low 16 = first arg
static __device__ __forceinline__ unsigned pk_bf16(float a, float b) {
    __hip_bfloat162 pk = __float22bfloat162_rn(make_float2(a, b));
    union { __hip_bfloat162 h; unsigned u; } v; v.h = pk;
    return v.u;
}

static __device__ __forceinline__ f32x4 mfma32(bf16x8 a, bf16x8 b, f32x4 c) {
    return __builtin_amdgcn_mfma_f32_16x16x32_bf16(a, b, c, 0, 0, 0);
}

// async global->LDS, 16B/lane; LDS dest = wave-uniform base + lane*16 (m97)
typedef __attribute__((address_space(3))) unsigned int lds_u32;
typedef __attribute__((address_space(1))) const unsigned int glb_u32;
static __device__ __forceinline__ void glds16(const unsigned short* g, unsigned short* l) {
    __builtin_amdgcn_global_load_lds((glb_u32*)g, (lds_u32*)l, 16, 0, 0);
}

// ---------------------------------------------------------------------------
// Merged prep: conv x->bf16 | transpose w_qkv | transpose w_proj.
// ---------------------------------------------------------------------------
#define PREP_CONV_ 1536   // 4096*768/(256*8)
#define PREP_TQKV_ 1728   // (2304/32)*(768/32)
#define PREP_TPRJ_ 576    // (768/32)*(768/32)
__global__ __launch_bounds__(256) void prep_kernel(
    const float* __restrict__ x,      unsigned short* __restrict__ x16,
    const float* __restrict__ w_qkv,  unsigned short* __restrict__ wqkvT,
    const float* __restrict__ w_proj, unsigned short* __restrict__ wprojT)
{
    __shared__ float tile[32][33];
    const int bid = blockIdx.x, t = threadIdx.x;
    if (bid < PREP_CONV_) {
        const int i = (bid * 256 + t) * 8;
        float4 a0 = *(const float4*)(x + i);
        float4 a1 = *(const float4*)(x + i + 4);
        u16x8 s;
        s[0] = f2bf(a0.x); s[1] = f2bf(a0.y); s[2] = f2bf(a0.z); s[3] = f2bf(a0.w);
        s[4] = f2bf(a1.x); s[5] = f2bf(a1.y); s[6] = f2bf(a1.z); s[7] = f2bf(a1.w);
        *(u16x8*)(x16 + i) = s;
        return;
    }
    const float* w; unsigned short* wT; int N, bb;
    if (bid < PREP_CONV_ + PREP_TQKV_) { w = w_qkv; wT = wqkvT; N = 3 * D_; bb = bid - PREP_CONV_; }
    else                               { w = w_proj; wT = wprojT; N = D_;   bb = bid - PREP_CONV_ - PREP_TQKV_; }
    const int K = D_;
    const int nt = N / 32;
    const int n0 = (bb % nt) * 32, k0 = (bb / nt) * 32;
    const int tx = t & 31, ty = t >> 5;
#pragma unroll
    for (int i = 0; i < 4; i++)
        tile[ty + i * 8][tx] = w[(size_t)(k0 + ty + i * 8) * N + n0 + tx];
    __syncthreads();
#pragma unroll
    for (int i = 0; i < 4; i++)
        wT[(size_t)(n0 + ty + i * 8) * K + k0 + tx] = f2bf(tile[tx][ty + i * 8]);
}

// ---------------------------------------------------------------------------
// Pure-bf16 GEMM + bias: C[M][N] = A[M][K] . Bt[N][K]^T + bias[N]
// r30: BK=64 rows (128B = 8 x 16B groups), XOR-swizzled g^(row&7) on both
// staging (pre-swizzled glds16 source, linear LDS dest) and frag reads
// (phys group = (quad + k2*4) ^ (row&7)) -> 2-way bank aliasing max (free).
// 12 K-iters (was 24) -> half the barrier drains. 4 waves, quadrant split.
// ---------------------------------------------------------------------------
template <int BM, int BN, bool OUT_F32>
__global__ __launch_bounds__(256) void gemm_bt_kernel(
    const unsigned short* __restrict__ A,
    const unsigned short* __restrict__ Bt,
    const float* __restrict__ bias,
    void* __restrict__ Cp,
    int M, int N, int K)
{
    constexpr int BK = 64;
    __shared__ __align__(16) unsigned short As[BM][BK];
    __shared__ __align__(16) unsigned short Bs[BN][BK];
    constexpr int MI = BM / 32, NJ = BN / 32;     // frags per wave quadrant
    constexpr int ACH = BM * BK / 8;              // 16B chunks per A tile
    constexpr int BCH = BN * BK / 8;

    const int t = threadIdx.x;
    const int w = t >> 6, lane = t & 63, quad = lane >> 4, l16 = lane & 15;
    const int n0 = blockIdx.x * BN, m0 = blockIdx.y * BM;
    const int mw = (w & 1) * (BM / 2), nw = (w >> 1) * (BN / 2);

    const f32x4 z = {0.f, 0.f, 0.f, 0.f};
    f32x4 acc[MI][NJ];
#pragma unroll
    for (int i = 0; i < MI; i++)
#pragma unroll
        for (int j = 0; j < NJ; j++) acc[i][j] = z;

    for (int kk = 0; kk < K; kk += BK) {
        // stage A: chunk c -> slot (row=c>>3, p=c&7) holds logical group
        // p^(row&7); source global group gs = (c&7)^(row&7).
#pragma unroll
        for (int it = 0; it < ACH / 256; it++) {
            const int c = t + it * 256;
            const int row = c >> 3, gs = (c & 7) ^ (row & 7);
            glds16(A + (size_t)(m0 + row) * K + kk + gs * 8, &As[0][0] + c * 8);
        }
#pragma unroll
        for (int it = 0; it < BCH / 256; it++) {
            const int c = t + it * 256;
            const int row = c >> 3, gs = (c & 7) ^ (row & 7);
            glds16(Bt + (size_t)(n0 + row) * K + kk + gs * 8, &Bs[0][0] + c * 8);
        }
        __syncthreads();

#pragma unroll
        for (int k2 = 0; k2 < 2; k2++) {
            bf16x8 a[MI], b[NJ];
#pragma unroll
            for (int i = 0; i < MI; i++) {
                const int row = mw + i * 16 + l16;
                const int p = (quad + k2 * 4) ^ (row & 7);
                a[i] = *(const bf16x8*)(&As[row][p * 8]);
            }
#pragma unroll
            for (int j = 0; j < NJ; j++) {
                const int row = nw + j * 16 + l16;
                const int p = (quad + k2 * 4) ^ (row & 7);
                b[j] = *(const bf16x8*)(&Bs[row][p * 8]);
            }
#pragma unroll
            for (int i = 0; i < MI; i++)
#pragma unroll
                for (int j = 0; j < NJ; j++)
                    acc[i][j] = mfma32(a[i], b[j], acc[i][j]);
        }
        __syncthreads();
    }

#pragma unroll
    for (int j = 0; j < NJ; j++) {
        const int col = n0 + nw + j * 16 + l16;
        const float bv = bias[col];
#pragma unroll
        for (int i = 0; i < MI; i++) {
#pragma unroll
            for (int r = 0; r < 4; r++) {
                const int row = m0 + mw + i * 16 + quad * 4 + r;
                const float v = acc[i][j][r] + bv;
                if (OUT_F32) ((float*)Cp)[(size_t)row * N + col] = v;
                else         ((unsigned short*)Cp)[(size_t)row * N + col] = f2bf(v);
            }
        }
    }
}

// ---------------------------------------------------------------------------
// Repack V (r10, measured good): LDS-tiled transpose, coalesced both sides.
// ---------------------------------------------------------------------------
__global__ __launch_bounds__(256) void repack_v_kernel(
    const unsigned short* __restrict__ qkv,
    unsigned short* __restrict__ vt)
{
    __shared__ unsigned short T[64][65];
    const int t = threadIdx.x;
    const int bh = blockIdx.x, st = blockIdx.y;
    const int b = bh / H_, h = bh % H_;
    const unsigned short* src =
        qkv + (size_t)(b * S_ + st * 64) * (3 * D_) + 2 * D_ + h * HD_;

#pragma unroll
    for (int it = 0; it < 2; it++) {
        const int c = t + it * 256, sr = c >> 3, g = c & 7;
        u16x8 v = *(const u16x8*)(src + (size_t)sr * (3 * D_) + g * 8);
#pragma unroll
        for (int j = 0; j < 8; j++) T[sr][g * 8 + j] = v[j];
    }
    __syncthreads();
#pragma unroll
    for (int it = 0; it < 2; it++) {
        const int c = t + it * 256, hd = c >> 3, g = c & 7;
        u16x8 v;
#pragma unroll
        for (int j = 0; j < 8; j++) v[j] = T[g * 8 + j][hd];
        *(u16x8*)(vt + (size_t)(bh * HD_ + hd) * S_ + st * 64 + g * 8) = v;
    }
}

// ---------------------------------------------------------------------------
// Flash attention — r26 body (measured 55.2us) + setprio around MFMA
// clusters (T5). Key-split over blockIdx.z (2 halves of 1024 keys); K and V
// glds16-staged into swizzled LDS with dbuf; emits UNNORMALIZED f32 partial
// o and per-(row,head) l. Combine done by the (correct, stream-ordered)
// combine_kernel.
//
// Key-row permutation (r22, verified): A-frag row l16 of tile-slice nt reads
// Ks row rowp = (nt>>1)*32 + (l16>>2)*8 + (nt&1)*4 + (l16&3) =>
// s_acc[nt][r] = S[key=(nt>>1)*32+quad*8+(nt&1)*4+r][q=l16]; packed pa0/pa1
// are exactly the PV A-frags. Ks swizzle sK(row)=(row&3)|((row>>3&1)<<2);
// Vs swizzle g^(row&7); glds16 with pre-swizzled global source.
// l-ones: mfma(pa, ones) -> C rows match o_acc rows; l[r] lane-local.
// ---------------------------------------------------------------------------
__global__ __launch_bounds__(256) void attn_kernel(
    const unsigned short* __restrict__ qkv,  // [B*S][3*D] bf16
    const unsigned short* __restrict__ vt,   // [B*H][HD][S] bf16
    float* __restrict__ o_p0,                // [B*S][D] f32 partial, half 0
    float* __restrict__ o_p1,                // [B*S][D] f32 partial, half 1
    float* __restrict__ l_p)                 // [2][B*S][H] f32
{
    __shared__ __align__(16) unsigned short Ks[2][64][64];   // [key][hd], sK swizzle
    __shared__ __align__(16) unsigned short Vs[2][64][64];   // [hd][key], g^(row&7)

    const int t = threadIdx.x;
    const int w = t >> 6, lane = t & 63, quad = lane >> 4, l16 = lane & 15;
    const int h8 = l16 & 7;
    const int qt = blockIdx.x, bh = blockIdx.y, ks = blockIdx.z;
    const int b = bh / H_, h = bh % H_;
    const int ld = 3 * D_;  // 2304

    // Q B-frags (n=l16 -> q row, k=quad*8+j), prescaled by SCALE*log2e
    const unsigned short* qbase =
        qkv + (size_t)(b * S_ + qt * 64 + 16 * w + l16) * ld + h * HD_;
    u16x8 qr0 = *(const u16x8*)(qbase + quad * 8);
    u16x8 qr1 = *(const u16x8*)(qbase + 32 + quad * 8);
    bf16x8 qf0, qf1;
#pragma unroll
    for (int j = 0; j < 8; j++) {
        qf0[j] = (short)f2bf(bf2f(qr0[j]) * EXP2C_);
        qf1[j] = (short)f2bf(bf2f(qr1[j]) * EXP2C_);
    }

    bf16x8 ones;
#pragma unroll
    for (int j = 0; j < 8; j++) ones[j] = (short)0x3F80;  // bf16 1.0

    // key-half base offsets (1024 keys per half)
    const unsigned short* kbase =
        qkv + (size_t)(b * S_ + ks * 1024) * ld + D_ + h * HD_;
    const unsigned short* vbase = vt + (size_t)bh * HD_ * S_;

    // per-lane staging source addresses (pre-swizzled global groups)
    const int c0 = t, c1 = t + 256;
    const int row0 = c0 >> 3, row1 = c1 >> 3;
    const int kg0 = (c0 & 7) ^ ((row0 & 3) | (((row0 >> 3) & 1) << 2));
    const int kg1 = (c1 & 7) ^ ((row1 & 3) | (((row1 >> 3) & 1) << 2));
    const int vg0 = (c0 & 7) ^ (row0 & 7);
    const int vg1 = (c1 & 7) ^ (row1 & 7);
    const unsigned short* kp0 = kbase + (size_t)row0 * ld + kg0 * 8;
    const unsigned short* kp1 = kbase + (size_t)row1 * ld + kg1 * 8;
    const unsigned short* vp0 = vbase + (size_t)row0 * S_ + ks * 1024 + vg0 * 8;
    const unsigned short* vp1 = vbase + (size_t)row1 * S_ + ks * 1024 + vg1 * 8;
    const size_t KSTEP = (size_t)64 * ld;  // elements per KV tile (K side)

    const f32x4 z = {0.f, 0.f, 0.f, 0.f};
    f32x4 o_acc[4] = {z, z, z, z};
    f32x4 l_acc = z;

    // prologue: stage tile 0 into buf 0
    glds16(kp0, &Ks[0][0][0] + c0 * 8);
    glds16(kp1, &Ks[0][0][0] + c1 * 8);
    glds16(vp0, &Vs[0][0][0] + c0 * 8);
    glds16(vp1, &Vs[0][0][0] + c1 * 8);
    kp0 += KSTEP; kp1 += KSTEP; vp0 += 64; vp1 += 64;
    __syncthreads();

    const int NT = 1024 / 64;  // 16 tiles per half
    for (int kt = 0; kt < NT; kt++) {
        const int buf = kt & 1;

        // prefetch tile kt+1 into buf^1 (async, drains at the barrier)
        if (kt + 1 < NT) {
            unsigned short* kd = &Ks[buf ^ 1][0][0];
            unsigned short* vd = &Vs[buf ^ 1][0][0];
            glds16(kp0, kd + c0 * 8);
            glds16(kp1, kd + c1 * 8);
            glds16(vp0, vd + c0 * 8);
            glds16(vp1, vd + c1 * 8);
            kp0 += KSTEP; kp1 += KSTEP; vp0 += 64; vp1 += 64;
        }

        // S^T = K . Q^T from LDS: s_acc[nt][r] = S[key=perm(nt,quad*4+r)][q=l16]
        f32x4 s_acc[4] = {z, z, z, z};
        __builtin_amdgcn_s_setprio(1);
#pragma unroll
        for (int nt = 0; nt < 4; nt++) {
            const int rowp = ((nt >> 1) << 5) + ((l16 >> 2) << 3) + ((nt & 1) << 2) + (l16 & 3);
            const int skr = (rowp & 3) | (((rowp >> 3) & 1) << 2);
            const unsigned short* kr = &Ks[buf][rowp][0];
            bf16x8 k0 = *(const bf16x8*)(kr + (quad ^ skr) * 8);
            bf16x8 k1 = *(const bf16x8*)(kr + ((quad ^ skr) ^ 4) * 8);
            s_acc[nt] = mfma32(k0, qf0, s_acc[nt]);
            s_acc[nt] = mfma32(k1, qf1, s_acc[nt]);
        }
        __builtin_amdgcn_s_setprio(0);

        // V-frag reads issued early; lgkm latency hides under exp2/pack
        bf16x8 vr0[4], vr1[4];
#pragma unroll
        for (int nt = 0; nt < 4; nt++) {
            const int row = nt * 16 + l16;
            vr0[nt] = *(const bf16x8*)(&Vs[buf][row][(quad ^ h8) * 8]);
            vr1[nt] = *(const bf16x8*)(&Vs[buf][row][((quad ^ h8) ^ 4) * 8]);
        }

        // p = exp2(s); pack to PV A-frags in registers
        f32x4 pr[4];
#pragma unroll
        for (int nt = 0; nt < 4; nt++) {
#pragma unroll
            for (int r = 0; r < 4; r++) pr[nt][r] = fexp2(s_acc[nt][r]);
        }
        union { u32x4 u; bf16x8 h; } ca, cb;
        ca.u[0] = pk_bf16(pr[0][0], pr[0][1]);
        ca.u[1] = pk_bf16(pr[0][2], pr[0][3]);
        ca.u[2] = pk_bf16(pr[1][0], pr[1][1]);
        ca.u[3] = pk_bf16(pr[1][2], pr[1][3]);
        cb.u[0] = pk_bf16(pr[2][0], pr[2][1]);
        cb.u[1] = pk_bf16(pr[2][2], pr[2][3]);
        cb.u[2] = pk_bf16(pr[3][0], pr[3][1]);
        cb.u[3] = pk_bf16(pr[3][2], pr[3][3]);
        const bf16x8 pa0 = ca.h, pa1 = cb.h;

        // l + O on the MFMA pipe (setprio: keep the matrix pipe fed)
        __builtin_amdgcn_s_setprio(1);
        l_acc = mfma32(pa0, ones, l_acc);
        l_acc = mfma32(pa1, ones, l_acc);
#pragma unroll
        for (int nt = 0; nt < 4; nt++) {
            o_acc[nt] = mfma32(pa0, vr0[nt], o_acc[nt]);
            o_acc[nt] = mfma32(pa1, vr1[nt], o_acc[nt]);
        }
        __builtin_amdgcn_s_setprio(0);

        __syncthreads();  // drains glds16 (vmcnt) -> buf^1 complete
    }

    // epilogue: write unnormalized f32 partials + l (lane-local, no shuffles)
    float* op = ks ? o_p1 : o_p0;
    float* lp2 = l_p + (size_t)ks * (B_ * S_ * H_);
#pragma unroll
    for (int r = 0; r < 4; r++) {
        const int row = b * S_ + qt * 64 + 16 * w + quad * 4 + r;
        float* ob = op + (size_t)row * D_ + h * HD_;
#pragma unroll
        for (int nt = 0; nt < 4; nt++)
            ob[nt * 16 + l16] = o_acc[nt][r];
        if (l16 == 0) lp2[(size_t)row * H_ + h] = l_acc[r];
    }
}

// ---------------------------------------------------------------------------
// Combine: o = (o0 + o1) / (l0 + l1), emit bf16 for GEMM2.
// Each thread: 8 cols (always within one head since 64 % 8 == 0).
// ---------------------------------------------------------------------------
__global__ __launch_bounds__(256) void combine_kernel(
    const float* __restrict__ o_p0,
    const float* __restrict__ o_p1,
    const float* __restrict__ l_p,
    unsigned short* __restrict__ o)
{
    const int i = (blockIdx.x * 256 + threadIdx.x) * 8;
    const int row = i / D_, col = i - row * D_, h = col >> 6;
    const float l0 = l_p[(size_t)row * H_ + h];
    const float l1 = l_p[(size_t)(B_ * S_ * H_) + row * H_ + h];
    const float inv = 1.f / (l0 + l1);
    float4 a0 = *(const float4*)(o_p0 + i);
    float4 a1 = *(const float4*)(o_p0 + i + 4);
    float4 b0 = *(const float4*)(o_p1 + i);
    float4 b1 = *(const float4*)(o_p1 + i + 4);
    u16x8 s;
    s[0] = f2bf((a0.x + b0.x) * inv); s[1] = f2bf((a0.y + b0.y) * inv);
    s[2] = f2bf((a0.z + b0.z) * inv); s[3] = f2bf((a0.w + b0.w) * inv);
    s[4] = f2bf((a1.x + b1.x) * inv); s[5] = f2bf((a1.y + b1.y) * inv);
    s[6] = f2bf((a1.z + b1.z) * inv); s[7] = f2bf((a1.w + b1.w) * inv);
    *(u16x8*)(o + i) = s;
}

// ---------------------------------------------------------------------------
extern "C" void kernel_launch(void* const* d_in, const int* in_sizes, int n_in,
                              void* d_out, int out_size, void* d_ws, size_t ws_size,
                              hipStream_t stream) {
    const float* x      = (const float*)d_in[0];  // [4096][768]
    const float* w_qkv  = (const float*)d_in[1];  // [768][2304]
    const float* b_qkv  = (const float*)d_in[2];  // [2304]
    const float* w_proj = (const float*)d_in[3];  // [768][768]
    const float* b_proj = (const float*)d_in[4];  // [768]
    float* out = (float*)d_out;                   // [4096][768]

    // ws carve (bf16 elements). x16 ALIASES o: GEMM1 consumes x16 before
    // attn writes o. o-partial half 0 reuses d_out as f32 scratch (GEMM2
    // overwrites it at the end); half 1 + l partials appended to ws.
    unsigned short* qkv    = (unsigned short*)d_ws;                     // 9,437,184
    unsigned short* vtb    = qkv    + (size_t)(B_ * S_) * (3 * D_);     // 3,145,728
    unsigned short* o_x16  = vtb    + (size_t)(B_ * H_) * HD_ * S_;     // 3,145,728
    unsigned short* wqkvT  = o_x16  + (size_t)(B_ * S_) * D_;           // 1,769,472
    unsigned short* wprojT = wqkvT  + (size_t)D_ * (3 * D_);            //   589,824
    float* o_p1 = (float*)(wprojT + (size_t)D_ * D_);                   // 3,145,728 f32
    float* l_p  = o_p1 + (size_t)(B_ * S_) * D_;                        // 2*4096*12 f32
    float* o_p0 = out;  // d_out as scratch

    dim3 blk(256);
    prep_kernel<<<dim3(PREP_CONV_ + PREP_TQKV_ + PREP_TPRJ_), blk, 0, stream>>>(
        x, o_x16, w_qkv, wqkvT, w_proj, wprojT);
    gemm_bt_kernel<128, 96, false><<<dim3((3 * D_) / 96, (B_ * S_) / 128), blk, 0, stream>>>(
        o_x16, wqkvT, b_qkv, qkv, B_ * S_, 3 * D_, D_);
    repack_v_kernel<<<dim3(B_ * H_, S_ / 64), blk, 0, stream>>>(qkv, vtb);
    attn_kernel<<<dim3(S_ / 64, B_ * H_, 2), blk, 0, stream>>>(qkv, vtb, o_p0, o_p1, l_p);
    combine_kernel<<<dim3((B_ * S_) * D_ / (256 * 8)), blk, 0, stream>>>(
        o_p0, o_p1, l_p, o_x16);
    gemm_bt_kernel<64, 64, true><<<dim3(D_ / 64, (B_ * S_) / 64), blk, 0, stream>>>(
        o_x16, wprojT, b_proj, out, B_ * S_, D_, D_);
}

// Round 10
// 165.475 us; speedup vs baseline: 1.1463x; 1.0349x over previous
//
#include <hip/hip_runtime.h>
#include <hip/hip_bf16.h>

// Problem: B=2, S=2048, D=768, H=12, HD=64. fp32 in/out, bf16 MFMA inside.
// r31 = r30 (171.2us champion) with:
// (1) attn setprio REVERTED (within-session A/B: r26/r28 attn 55.2/56.2 vs
//     r30 59.0 — lockstep 4-wave barriers are m190's null/negative regime).
// (2) attn XCD-aware block remap: FETCH 54MB vs 19MB ideal = 2.8x overfetch
//     because the 32 qt-blocks sharing a head's K/V round-robin across all
//     8 XCDs. Remap id -> xcd=id&7, grp=xcd*6+(ix>>5), qt=ix&31: each XCD
//     owns 6 whole (bh,ks) groups -> K/V L2-resident (1.5MB/XCD), staging
//     becomes L2-hit -> smaller barrier-drain stall.
// (3) repack_v FOLDED into GEMM1 epilogue: V-tile blocks (n0>=1536; BN=96
//     divides the boundary) write C directly transposed into vt (4 consec
//     s per thread = one 8B store). Deletes the repack kernel (12.6MB +
//     launch). Math identical: f2bf(acc + bias).
// Win ledger: r4 LDS staging+dbuf, r5 xor-swizzle, r15 GEMM2 64x64,
// r18 GEMM1 128x96, r22 swapped-QK^T in-register P, r24 glds16 pre-swizzled
// staging + l-on-MFMA, r26 key-split (attn 55.2), r30 GEMM BK=64 swizzle
// (total 176.3->171.2).
// Failure ledger (do not revisit): r7 mfma16, r8 wave-split, r11 32x32 MFMA,
// r12 attn BK=64, r9/r13/r14 math micro-opts, r16 GEMM1 64x128, r20 GEMM2
// dbuf, r23 2-wave/32q blocks, r25 V-direct-global mid-iter, r27 V-reg
// prefetch post-PV, r28 gemm2-fused combine, r29 cross-block combine
// (XCD non-coherent -> tripwire FAIL), r30 attn setprio (+3us, lockstep).
#define B_ 2
#define S_ 2048
#define D_ 768
#define H_ 12
#define HD_ 64
#define EXP2C_ 0.1803368801111244f  // SCALE * log2(e), folded into Q

typedef __attribute__((ext_vector_type(8))) short bf16x8;
typedef __attribute__((ext_vector_type(8))) unsigned short u16x8;
typedef __attribute__((ext_vector_type(4))) float f32x4;
typedef __attribute__((ext_vector_type(4))) unsigned int u32x4;

static __device__ __forceinline__ unsigned short f2bf(float x) {
    union { float f; unsigned u; } v; v.f = x;
    unsigned r = (v.u + 0x7FFFu + ((v.u >> 16) & 1u)) >> 16;  // RNE
    return (unsigned short)r;
}
static __device__ __forceinline__ float bf2f(unsigned short h) {
    union { unsigned u; float f; } v; v.u = ((unsigned)h) << 16;
    return v.f;
}
static __device__ __forceinline__ float fexp2(float x) { return __builtin_exp2f(x); }

// packed f32x2 -> bf16x2 (v_cvt_pk_bf16_f32) as raw u32; low 16 = first arg
static __device__ __forceinline__ unsigned pk_bf16(float a, float b) {
    __hip_bfloat162 pk = __float22bfloat162_rn(make_float2(a, b));
    union { __hip_bfloat162 h; unsigned u; } v; v.h = pk;
    return v.u;
}

static __device__ __forceinline__ f32x4 mfma32(bf16x8 a, bf16x8 b, f32x4 c) {
    return __builtin_amdgcn_mfma_f32_16x16x32_bf16(a, b, c, 0, 0, 0);
}

// async global->LDS, 16B/lane; LDS dest = wave-uniform base + lane*16 (m97)
typedef __attribute__((address_space(3))) unsigned int lds_u32;
typedef __attribute__((address_space(1))) const unsigned int glb_u32;
static __device__ __forceinline__ void glds16(const unsigned short* g, unsigned short* l) {
    __builtin_amdgcn_global_load_lds((glb_u32*)g, (lds_u32*)l, 16, 0, 0);
}

// ---------------------------------------------------------------------------
// Merged prep: conv x->bf16 | transpose w_qkv | transpose w_proj.
// ---------------------------------------------------------------------------
#define PREP_CONV_ 1536   // 4096*768/(256*8)
#define PREP_TQKV_ 1728   // (2304/32)*(768/32)
#define PREP_TPRJ_ 576    // (768/32)*(768/32)
__global__ __launch_bounds__(256) void prep_kernel(
    const float* __restrict__ x,      unsigned short* __restrict__ x16,
    const float* __restrict__ w_qkv,  unsigned short* __restrict__ wqkvT,
    const float* __restrict__ w_proj, unsigned short* __restrict__ wprojT)
{
    __shared__ float tile[32][33];
    const int bid = blockIdx.x, t = threadIdx.x;
    if (bid < PREP_CONV_) {
        const int i = (bid * 256 + t) * 8;
        float4 a0 = *(const float4*)(x + i);
        float4 a1 = *(const float4*)(x + i + 4);
        u16x8 s;
        s[0] = f2bf(a0.x); s[1] = f2bf(a0.y); s[2] = f2bf(a0.z); s[3] = f2bf(a0.w);
        s[4] = f2bf(a1.x); s[5] = f2bf(a1.y); s[6] = f2bf(a1.z); s[7] = f2bf(a1.w);
        *(u16x8*)(x16 + i) = s;
        return;
    }
    const float* w; unsigned short* wT; int N, bb;
    if (bid < PREP_CONV_ + PREP_TQKV_) { w = w_qkv; wT = wqkvT; N = 3 * D_; bb = bid - PREP_CONV_; }
    else                               { w = w_proj; wT = wprojT; N = D_;   bb = bid - PREP_CONV_ - PREP_TQKV_; }
    const int K = D_;
    const int nt = N / 32;
    const int n0 = (bb % nt) * 32, k0 = (bb / nt) * 32;
    const int tx = t & 31, ty = t >> 5;
#pragma unroll
    for (int i = 0; i < 4; i++)
        tile[ty + i * 8][tx] = w[(size_t)(k0 + ty + i * 8) * N + n0 + tx];
    __syncthreads();
#pragma unroll
    for (int i = 0; i < 4; i++)
        wT[(size_t)(n0 + ty + i * 8) * K + k0 + tx] = f2bf(tile[tx][ty + i * 8]);
}

// ---------------------------------------------------------------------------
// Pure-bf16 GEMM + bias (r30 structure): BK=64 rows (128B = 8 x 16B groups),
// XOR-swizzled g^(row&7) on staging (pre-swizzled glds16 source, linear LDS
// dest) and frag reads ((quad+k2*4)^(row&7)) -> <=2-way (free).
// r31: VSPLIT epilogue — V-region blocks (n0 >= 2D) write C transposed
// directly into vt[bh][hd][s] (4 consecutive s per thread = one 8B store).
// ---------------------------------------------------------------------------
template <int BM, int BN, bool OUT_F32, bool VSPLIT>
__global__ __launch_bounds__(256) void gemm_bt_kernel(
    const unsigned short* __restrict__ A,
    const unsigned short* __restrict__ Bt,
    const float* __restrict__ bias,
    void* __restrict__ Cp,
    unsigned short* __restrict__ vt,   // VSPLIT target (else unused)
    int M, int N, int K)
{
    constexpr int BK = 64;
    __shared__ __align__(16) unsigned short As[BM][BK];
    __shared__ __align__(16) unsigned short Bs[BN][BK];
    constexpr int MI = BM / 32, NJ = BN / 32;     // frags per wave quadrant
    constexpr int ACH = BM * BK / 8;              // 16B chunks per A tile
    constexpr int BCH = BN * BK / 8;

    const int t = threadIdx.x;
    const int w = t >> 6, lane = t & 63, quad = lane >> 4, l16 = lane & 15;
    const int n0 = blockIdx.x * BN, m0 = blockIdx.y * BM;
    const int mw = (w & 1) * (BM / 2), nw = (w >> 1) * (BN / 2);

    const f32x4 z = {0.f, 0.f, 0.f, 0.f};
    f32x4 acc[MI][NJ];
#pragma unroll
    for (int i = 0; i < MI; i++)
#pragma unroll
        for (int j = 0; j < NJ; j++) acc[i][j] = z;

    for (int kk = 0; kk < K; kk += BK) {
#pragma unroll
        for (int it = 0; it < ACH / 256; it++) {
            const int c = t + it * 256;
            const int row = c >> 3, gs = (c & 7) ^ (row & 7);
            glds16(A + (size_t)(m0 + row) * K + kk + gs * 8, &As[0][0] + c * 8);
        }
#pragma unroll
        for (int it = 0; it < BCH / 256; it++) {
            const int c = t + it * 256;
            const int row = c >> 3, gs = (c & 7) ^ (row & 7);
            glds16(Bt + (size_t)(n0 + row) * K + kk + gs * 8, &Bs[0][0] + c * 8);
        }
        __syncthreads();

#pragma unroll
        for (int k2 = 0; k2 < 2; k2++) {
            bf16x8 a[MI], b[NJ];
#pragma unroll
            for (int i = 0; i < MI; i++) {
                const int row = mw + i * 16 + l16;
                const int p = (quad + k2 * 4) ^ (row & 7);
                a[i] = *(const bf16x8*)(&As[row][p * 8]);
            }
#pragma unroll
            for (int j = 0; j < NJ; j++) {
                const int row = nw + j * 16 + l16;
                const int p = (quad + k2 * 4) ^ (row & 7);
                b[j] = *(const bf16x8*)(&Bs[row][p * 8]);
            }
#pragma unroll
            for (int i = 0; i < MI; i++)
#pragma unroll
                for (int j = 0; j < NJ; j++)
                    acc[i][j] = mfma32(a[i], b[j], acc[i][j]);
        }
        __syncthreads();
    }

    if (VSPLIT && n0 >= 2 * D_) {
        // V region: write transposed into vt[bh][hd][s], 4 consec s = 8B.
#pragma unroll
        for (int j = 0; j < NJ; j++) {
            const int gcol = n0 + nw + j * 16 + l16;
            const int col = gcol - 2 * D_;
            const int hh = col >> 6, hd = col & 63;
            const float bv = bias[gcol];
#pragma unroll
            for (int i = 0; i < MI; i++) {
                const int row = m0 + mw + i * 16 + quad * 4;
                const int bb = row >> 11, ss = row & 2047;
                unsigned long long pkv = 0;
#pragma unroll
                for (int r = 0; r < 4; r++)
                    pkv |= (unsigned long long)f2bf(acc[i][j][r] + bv) << (16 * r);
                *(unsigned long long*)(vt +
                    ((size_t)(bb * H_ + hh) * HD_ + hd) * S_ + ss) = pkv;
            }
        }
        return;
    }

#pragma unroll
    for (int j = 0; j < NJ; j++) {
        const int col = n0 + nw + j * 16 + l16;
        const float bv = bias[col];
#pragma unroll
        for (int i = 0; i < MI; i++) {
#pragma unroll
            for (int r = 0; r < 4; r++) {
                const int row = m0 + mw + i * 16 + quad * 4 + r;
                const float v = acc[i][j][r] + bv;
                if (OUT_F32) ((float*)Cp)[(size_t)row * N + col] = v;
                else         ((unsigned short*)Cp)[(size_t)row * N + col] = f2bf(v);
            }
        }
    }
}

// ---------------------------------------------------------------------------
// Flash attention — r26 body verbatim (measured 55.2us; no setprio) +
// XCD-aware 1D block remap: id -> xcd=id&7, ix=id>>3, grp=xcd*6+(ix>>5)
// (bh=grp>>1, ks=grp&1), qt=ix&31. Each XCD owns 6 whole (bh,ks) groups
// -> that XCD's L2 holds just 6 x 256KB of K/V (vs all 24 heads before).
// Key-split over ks (2 halves of 1024 keys); K/V glds16-staged into
// swizzled LDS dbuf; emits UNNORMALIZED f32 partial o + per-(row,head) l.
//
// Key-row permutation (r22, verified): A-frag row l16 of tile-slice nt reads
// Ks row rowp = (nt>>1)*32 + (l16>>2)*8 + (nt&1)*4 + (l16&3) =>
// s_acc[nt][r] = S[key=(nt>>1)*32+quad*8+(nt&1)*4+r][q=l16]; packed pa0/pa1
// are exactly the PV A-frags. Ks swizzle sK(row)=(row&3)|((row>>3&1)<<2);
// Vs swizzle g^(row&7); glds16 with pre-swizzled global source.
// l-ones: mfma(pa, ones) -> C rows match o_acc rows; l[r] lane-local.
// ---------------------------------------------------------------------------
__global__ __launch_bounds__(256) void attn_kernel(
    const unsigned short* __restrict__ qkv,  // [B*S][3*D] bf16 (Q,K cols only)
    const unsigned short* __restrict__ vt,   // [B*H][HD][S] bf16
    float* __restrict__ o_p0,                // [B*S][D] f32 partial, half 0
    float* __restrict__ o_p1,                // [B*S][D] f32 partial, half 1
    float* __restrict__ l_p)                 // [2][B*S][H] f32
{
    __shared__ __align__(16) unsigned short Ks[2][64][64];   // [key][hd], sK swizzle
    __shared__ __align__(16) unsigned short Vs[2][64][64];   // [hd][key], g^(row&7)

    const int t = threadIdx.x;
    const int w = t >> 6, lane = t & 63, quad = lane >> 4, l16 = lane & 15;
    const int h8 = l16 & 7;
    // XCD-aware decode (bijective over 1536 blocks; 8 XCDs round-robin)
    const int id = blockIdx.x;
    const int xcd = id & 7, ix = id >> 3;
    const int grp = xcd * 6 + (ix >> 5);     // 0..47 = bh*2 + ks
    const int qt = ix & 31;
    const int bh = grp >> 1, ks = grp & 1;
    const int b = bh / H_, h = bh % H_;
    const int ld = 3 * D_;  // 2304

    // Q B-frags (n=l16 -> q row, k=quad*8+j), prescaled by SCALE*log2e
    const unsigned short* qbase =
        qkv + (size_t)(b * S_ + qt * 64 + 16 * w + l16) * ld + h * HD_;
    u16x8 qr0 = *(const u16x8*)(qbase + quad * 8);
    u16x8 qr1 = *(const u16x8*)(qbase + 32 + quad * 8);
    bf16x8 qf0, qf1;
#pragma unroll
    for (int j = 0; j < 8; j++) {
        qf0[j] = (short)f2bf(bf2f(qr0[j]) * EXP2C_);
        qf1[j] = (short)f2bf(bf2f(qr1[j]) * EXP2C_);
    }

    bf16x8 ones;
#pragma unroll
    for (int j = 0; j < 8; j++) ones[j] = (short)0x3F80;  // bf16 1.0

    // key-half base offsets (1024 keys per half)
    const unsigned short* kbase =
        qkv + (size_t)(b * S_ + ks * 1024) * ld + D_ + h * HD_;
    const unsigned short* vbase = vt + (size_t)bh * HD_ * S_;

    // per-lane staging source addresses (pre-swizzled global groups)
    const int c0 = t, c1 = t + 256;
    const int row0 = c0 >> 3, row1 = c1 >> 3;
    const int kg0 = (c0 & 7) ^ ((row0 & 3) | (((row0 >> 3) & 1) << 2));
    const int kg1 = (c1 & 7) ^ ((row1 & 3) | (((row1 >> 3) & 1) << 2));
    const int vg0 = (c0 & 7) ^ (row0 & 7);
    const int vg1 = (c1 & 7) ^ (row1 & 7);
    const unsigned short* kp0 = kbase + (size_t)row0 * ld + kg0 * 8;
    const unsigned short* kp1 = kbase + (size_t)row1 * ld + kg1 * 8;
    const unsigned short* vp0 = vbase + (size_t)row0 * S_ + ks * 1024 + vg0 * 8;
    const unsigned short* vp1 = vbase + (size_t)row1 * S_ + ks * 1024 + vg1 * 8;
    const size_t KSTEP = (size_t)64 * ld;  // elements per KV tile (K side)

    const f32x4 z = {0.f, 0.f, 0.f, 0.f};
    f32x4 o_acc[4] = {z, z, z, z};
    f32x4 l_acc = z;

    // prologue: stage tile 0 into buf 0
    glds16(kp0, &Ks[0][0][0] + c0 * 8);
    glds16(kp1, &Ks[0][0][0] + c1 * 8);
    glds16(vp0, &Vs[0][0][0] + c0 * 8);
    glds16(vp1, &Vs[0][0][0] + c1 * 8);
    kp0 += KSTEP; kp1 += KSTEP; vp0 += 64; vp1 += 64;
    __syncthreads();

    const int NT = 1024 / 64;  // 16 tiles per half
    for (int kt = 0; kt < NT; kt++) {
        const int buf = kt & 1;

        // prefetch tile kt+1 into buf^1 (async, drains at the barrier)
        if (kt + 1 < NT) {
            unsigned short* kd = &Ks[buf ^ 1][0][0];
            unsigned short* vd = &Vs[buf ^ 1][0][0];
            glds16(kp0, kd + c0 * 8);
            glds16(kp1, kd + c1 * 8);
            glds16(vp0, vd + c0 * 8);
            glds16(vp1, vd + c1 * 8);
            kp0 += KSTEP; kp1 += KSTEP; vp0 += 64; vp1 += 64;
        }

        // S^T = K . Q^T from LDS: s_acc[nt][r] = S[key=perm(nt,quad*4+r)][q=l16]
        f32x4 s_acc[4] = {z, z, z, z};
#pragma unroll
        for (int nt = 0; nt < 4; nt++) {
            const int rowp = ((nt >> 1) << 5) + ((l16 >> 2) << 3) + ((nt & 1) << 2) + (l16 & 3);
            const int skr = (rowp & 3) | (((rowp >> 3) & 1) << 2);
            const unsigned short* kr = &Ks[buf][rowp][0];
            bf16x8 k0 = *(const bf16x8*)(kr + (quad ^ skr) * 8);
            bf16x8 k1 = *(const bf16x8*)(kr + ((quad ^ skr) ^ 4) * 8);
            s_acc[nt] = mfma32(k0, qf0, s_acc[nt]);
            s_acc[nt] = mfma32(k1, qf1, s_acc[nt]);
        }

        // V-frag reads issued early; lgkm latency hides under exp2/pack
        bf16x8 vr0[4], vr1[4];
#pragma unroll
        for (int nt = 0; nt < 4; nt++) {
            const int row = nt * 16 + l16;
            vr0[nt] = *(const bf16x8*)(&Vs[buf][row][(quad ^ h8) * 8]);
            vr1[nt] = *(const bf16x8*)(&Vs[buf][row][((quad ^ h8) ^ 4) * 8]);
        }

        // p = exp2(s); pack to PV A-frags in registers
        f32x4 pr[4];
#pragma unroll
        for (int nt = 0; nt < 4; nt++) {
#pragma unroll
            for (int r = 0; r < 4; r++) pr[nt][r] = fexp2(s_acc[nt][r]);
        }
        union { u32x4 u; bf16x8 h; } ca, cb;
        ca.u[0] = pk_bf16(pr[0][0], pr[0][1]);
        ca.u[1] = pk_bf16(pr[0][2], pr[0][3]);
        ca.u[2] = pk_bf16(pr[1][0], pr[1][1]);
        ca.u[3] = pk_bf16(pr[1][2], pr[1][3]);
        cb.u[0] = pk_bf16(pr[2][0], pr[2][1]);
        cb.u[1] = pk_bf16(pr[2][2], pr[2][3]);
        cb.u[2] = pk_bf16(pr[3][0], pr[3][1]);
        cb.u[3] = pk_bf16(pr[3][2], pr[3][3]);
        const bf16x8 pa0 = ca.h, pa1 = cb.h;

        // l on the MFMA pipe: C rows match o_acc rows, dup over cols
        l_acc = mfma32(pa0, ones, l_acc);
        l_acc = mfma32(pa1, ones, l_acc);

        // O += P . V from LDS (register V frags)
#pragma unroll
        for (int nt = 0; nt < 4; nt++) {
            o_acc[nt] = mfma32(pa0, vr0[nt], o_acc[nt]);
            o_acc[nt] = mfma32(pa1, vr1[nt], o_acc[nt]);
        }

        __syncthreads();  // drains glds16 (vmcnt) -> buf^1 complete
    }

    // epilogue: write unnormalized f32 partials + l (lane-local, no shuffles)
    float* op = ks ? o_p1 : o_p0;
    float* lp2 = l_p + (size_t)ks * (B_ * S_ * H_);
#pragma unroll
    for (int r = 0; r < 4; r++) {
        const int row = b * S_ + qt * 64 + 16 * w + quad * 4 + r;
        float* ob = op + (size_t)row * D_ + h * HD_;
#pragma unroll
        for (int nt = 0; nt < 4; nt++)
            ob[nt * 16 + l16] = o_acc[nt][r];
        if (l16 == 0) lp2[(size_t)row * H_ + h] = l_acc[r];
    }
}

// ---------------------------------------------------------------------------
// Combine: o = (o0 + o1) / (l0 + l1), emit bf16 for GEMM2.
// Each thread: 8 cols (always within one head since 64 % 8 == 0).
// ---------------------------------------------------------------------------
__global__ __launch_bounds__(256) void combine_kernel(
    const float* __restrict__ o_p0,
    const float* __restrict__ o_p1,
    const float* __restrict__ l_p,
    unsigned short* __restrict__ o)
{
    const int i = (blockIdx.x * 256 + threadIdx.x) * 8;
    const int row = i / D_, col = i - row * D_, h = col >> 6;
    const float l0 = l_p[(size_t)row * H_ + h];
    const float l1 = l_p[(size_t)(B_ * S_ * H_) + row * H_ + h];
    const float inv = 1.f / (l0 + l1);
    float4 a0 = *(const float4*)(o_p0 + i);
    float4 a1 = *(const float4*)(o_p0 + i + 4);
    float4 b0 = *(const float4*)(o_p1 + i);
    float4 b1 = *(const float4*)(o_p1 + i + 4);
    u16x8 s;
    s[0] = f2bf((a0.x + b0.x) * inv); s[1] = f2bf((a0.y + b0.y) * inv);
    s[2] = f2bf((a0.z + b0.z) * inv); s[3] = f2bf((a0.w + b0.w) * inv);
    s[4] = f2bf((a1.x + b1.x) * inv); s[5] = f2bf((a1.y + b1.y) * inv);
    s[6] = f2bf((a1.z + b1.z) * inv); s[7] = f2bf((a1.w + b1.w) * inv);
    *(u16x8*)(o + i) = s;
}

// ---------------------------------------------------------------------------
extern "C" void kernel_launch(void* const* d_in, const int* in_sizes, int n_in,
                              void* d_out, int out_size, void* d_ws, size_t ws_size,
                              hipStream_t stream) {
    const float* x      = (const float*)d_in[0];  // [4096][768]
    const float* w_qkv  = (const float*)d_in[1];  // [768][2304]
    const float* b_qkv  = (const float*)d_in[2];  // [2304]
    const float* w_proj = (const float*)d_in[3];  // [768][768]
    const float* b_proj = (const float*)d_in[4];  // [768]
    float* out = (float*)d_out;                   // [4096][768]

    // ws carve (bf16 elements). x16 ALIASES o: GEMM1 consumes x16 before
    // attn writes o. o-partial half 0 reuses d_out as f32 scratch (GEMM2
    // overwrites it at the end); half 1 + l partials appended to ws.
    unsigned short* qkv    = (unsigned short*)d_ws;                     // 9,437,184
    unsigned short* vtb    = qkv    + (size_t)(B_ * S_) * (3 * D_);     // 3,145,728
    unsigned short* o_x16  = vtb    + (size_t)(B_ * H_) * HD_ * S_;     // 3,145,728
    unsigned short* wqkvT  = o_x16  + (size_t)(B_ * S_) * D_;           // 1,769,472
    unsigned short* wprojT = wqkvT  + (size_t)D_ * (3 * D_);            //   589,824
    float* o_p1 = (float*)(wprojT + (size_t)D_ * D_);                   // 3,145,728 f32
    float* l_p  = o_p1 + (size_t)(B_ * S_) * D_;                        // 2*4096*12 f32
    float* o_p0 = out;  // d_out as scratch

    dim3 blk(256);
    prep_kernel<<<dim3(PREP_CONV_ + PREP_TQKV_ + PREP_TPRJ_), blk, 0, stream>>>(
        x, o_x16, w_qkv, wqkvT, w_proj, wprojT);
    gemm_bt_kernel<128, 96, false, true><<<dim3((3 * D_) / 96, (B_ * S_) / 128), blk, 0, stream>>>(
        o_x16, wqkvT, b_qkv, qkv, vtb, B_ * S_, 3 * D_, D_);
    attn_kernel<<<dim3((S_ / 64) * (B_ * H_) * 2), blk, 0, stream>>>(
        qkv, vtb, o_p0, o_p1, l_p);
    combine_kernel<<<dim3((B_ * S_) * D_ / (256 * 8)), blk, 0, stream>>>(
        o_p0, o_p1, l_p, o_x16);
    gemm_bt_kernel<64, 64, true, false><<<dim3(D_ / 64, (B_ * S_) / 64), blk, 0, stream>>>(
        o_x16, wprojT, b_proj, out, nullptr, B_ * S_, D_, D_);
}

// Round 11
// 163.103 us; speedup vs baseline: 1.1630x; 1.0145x over previous
//
#include <hip/hip_runtime.h>
#include <hip/hip_bf16.h>

// Problem: B=2, S=2048, D=768, H=12, HD=64. fp32 in/out, bf16 MFMA inside.
// r32 = r31 (165.5us champion) with SPLIT-K REVERTED on attn:
// within-session ledger shows split-k attn (55-57us) + combine (~7us) loses
// to unsplit attn (59.5us, no combine). Unsplit attn keeps the r31 XCD
// remap (xcd=id&7, grp=xcd*3+(ix>>5): 3 whole heads per XCD = 1.5MB K+V,
// L2-resident), l-on-MFMA, in-register normalize, direct bf16 o write.
// combine_kernel + f32 partials + d_out scratch deleted.
// Win ledger: r4 LDS staging+dbuf, r5 xor-swizzle, r15 GEMM2 64x64,
// r18 GEMM1 128x96, r22 swapped-QK^T in-register P, r24 glds16 pre-swizzled
// staging + l-on-MFMA, r30 GEMM BK=64 swizzle, r31 XCD remap (FETCH 54->9MB)
// + repack_v folded into GEMM1 epilogue.
// Failure ledger (do not revisit): r7 mfma16, r8 wave-split, r11 32x32 MFMA,
// r12 attn BK=64, r9/r13/r14 math micro-opts, r16 GEMM1 64x128, r20 GEMM2
// dbuf, r23 2-wave/32q blocks, r25 V-direct-global mid-iter, r27 V-reg
// prefetch post-PV, r28 gemm2-fused combine, r29 cross-block combine
// (XCD non-coherent -> tripwire FAIL), r30 attn setprio (lockstep regime),
// r26/r31 split-k (combine tax > occupancy gain).
#define B_ 2
#define S_ 2048
#define D_ 768
#define H_ 12
#define HD_ 64
#define EXP2C_ 0.1803368801111244f  // SCALE * log2(e), folded into Q

typedef __attribute__((ext_vector_type(8))) short bf16x8;
typedef __attribute__((ext_vector_type(8))) unsigned short u16x8;
typedef __attribute__((ext_vector_type(4))) float f32x4;
typedef __attribute__((ext_vector_type(4))) unsigned int u32x4;

static __device__ __forceinline__ unsigned short f2bf(float x) {
    union { float f; unsigned u; } v; v.f = x;
    unsigned r = (v.u + 0x7FFFu + ((v.u >> 16) & 1u)) >> 16;  // RNE
    return (unsigned short)r;
}
static __device__ __forceinline__ float bf2f(unsigned short h) {
    union { unsigned u; float f; } v; v.u = ((unsigned)h) << 16;
    return v.f;
}
static __device__ __forceinline__ float fexp2(float x) { return __builtin_exp2f(x); }

// packed f32x2 -> bf16x2 (v_cvt_pk_bf16_f32) as raw u32; low 16 = first arg
static __device__ __forceinline__ unsigned pk_bf16(float a, float b) {
    __hip_bfloat162 pk = __float22bfloat162_rn(make_float2(a, b));
    union { __hip_bfloat162 h; unsigned u; } v; v.h = pk;
    return v.u;
}

static __device__ __forceinline__ f32x4 mfma32(bf16x8 a, bf16x8 b, f32x4 c) {
    return __builtin_amdgcn_mfma_f32_16x16x32_bf16(a, b, c, 0, 0, 0);
}

// async global->LDS, 16B/lane; LDS dest = wave-uniform base + lane*16 (m97)
typedef __attribute__((address_space(3))) unsigned int lds_u32;
typedef __attribute__((address_space(1))) const unsigned int glb_u32;
static __device__ __forceinline__ void glds16(const unsigned short* g, unsigned short* l) {
    __builtin_amdgcn_global_load_lds((glb_u32*)g, (lds_u32*)l, 16, 0, 0);
}

// ---------------------------------------------------------------------------
// Merged prep: conv x->bf16 | transpose w_qkv | transpose w_proj.
// ---------------------------------------------------------------------------
#define PREP_CONV_ 1536   // 4096*768/(256*8)
#define PREP_TQKV_ 1728   // (2304/32)*(768/32)
#define PREP_TPRJ_ 576    // (768/32)*(768/32)
__global__ __launch_bounds__(256) void prep_kernel(
    const float* __restrict__ x,      unsigned short* __restrict__ x16,
    const float* __restrict__ w_qkv,  unsigned short* __restrict__ wqkvT,
    const float* __restrict__ w_proj, unsigned short* __restrict__ wprojT)
{
    __shared__ float tile[32][33];
    const int bid = blockIdx.x, t = threadIdx.x;
    if (bid < PREP_CONV_) {
        const int i = (bid * 256 + t) * 8;
        float4 a0 = *(const float4*)(x + i);
        float4 a1 = *(const float4*)(x + i + 4);
        u16x8 s;
        s[0] = f2bf(a0.x); s[1] = f2bf(a0.y); s[2] = f2bf(a0.z); s[3] = f2bf(a0.w);
        s[4] = f2bf(a1.x); s[5] = f2bf(a1.y); s[6] = f2bf(a1.z); s[7] = f2bf(a1.w);
        *(u16x8*)(x16 + i) = s;
        return;
    }
    const float* w; unsigned short* wT; int N, bb;
    if (bid < PREP_CONV_ + PREP_TQKV_) { w = w_qkv; wT = wqkvT; N = 3 * D_; bb = bid - PREP_CONV_; }
    else                               { w = w_proj; wT = wprojT; N = D_;   bb = bid - PREP_CONV_ - PREP_TQKV_; }
    const int K = D_;
    const int nt = N / 32;
    const int n0 = (bb % nt) * 32, k0 = (bb / nt) * 32;
    const int tx = t & 31, ty = t >> 5;
#pragma unroll
    for (int i = 0; i < 4; i++)
        tile[ty + i * 8][tx] = w[(size_t)(k0 + ty + i * 8) * N + n0 + tx];
    __syncthreads();
#pragma unroll
    for (int i = 0; i < 4; i++)
        wT[(size_t)(n0 + ty + i * 8) * K + k0 + tx] = f2bf(tile[tx][ty + i * 8]);
}

// ---------------------------------------------------------------------------
// Pure-bf16 GEMM + bias (r30 structure): BK=64 rows (128B = 8 x 16B groups),
// XOR-swizzled g^(row&7) on staging (pre-swizzled glds16 source, linear LDS
// dest) and frag reads ((quad+k2*4)^(row&7)) -> <=2-way (free).
// VSPLIT epilogue (r31): V-region blocks (n0 >= 2D) write C transposed
// directly into vt[bh][hd][s] (4 consecutive s per thread = one 8B store).
// ---------------------------------------------------------------------------
template <int BM, int BN, bool OUT_F32, bool VSPLIT>
__global__ __launch_bounds__(256) void gemm_bt_kernel(
    const unsigned short* __restrict__ A,
    const unsigned short* __restrict__ Bt,
    const float* __restrict__ bias,
    void* __restrict__ Cp,
    unsigned short* __restrict__ vt,   // VSPLIT target (else unused)
    int M, int N, int K)
{
    constexpr int BK = 64;
    __shared__ __align__(16) unsigned short As[BM][BK];
    __shared__ __align__(16) unsigned short Bs[BN][BK];
    constexpr int MI = BM / 32, NJ = BN / 32;     // frags per wave quadrant
    constexpr int ACH = BM * BK / 8;              // 16B chunks per A tile
    constexpr int BCH = BN * BK / 8;

    const int t = threadIdx.x;
    const int w = t >> 6, lane = t & 63, quad = lane >> 4, l16 = lane & 15;
    const int n0 = blockIdx.x * BN, m0 = blockIdx.y * BM;
    const int mw = (w & 1) * (BM / 2), nw = (w >> 1) * (BN / 2);

    const f32x4 z = {0.f, 0.f, 0.f, 0.f};
    f32x4 acc[MI][NJ];
#pragma unroll
    for (int i = 0; i < MI; i++)
#pragma unroll
        for (int j = 0; j < NJ; j++) acc[i][j] = z;

    for (int kk = 0; kk < K; kk += BK) {
#pragma unroll
        for (int it = 0; it < ACH / 256; it++) {
            const int c = t + it * 256;
            const int row = c >> 3, gs = (c & 7) ^ (row & 7);
            glds16(A + (size_t)(m0 + row) * K + kk + gs * 8, &As[0][0] + c * 8);
        }
#pragma unroll
        for (int it = 0; it < BCH / 256; it++) {
            const int c = t + it * 256;
            const int row = c >> 3, gs = (c & 7) ^ (row & 7);
            glds16(Bt + (size_t)(n0 + row) * K + kk + gs * 8, &Bs[0][0] + c * 8);
        }
        __syncthreads();

#pragma unroll
        for (int k2 = 0; k2 < 2; k2++) {
            bf16x8 a[MI], b[NJ];
#pragma unroll
            for (int i = 0; i < MI; i++) {
                const int row = mw + i * 16 + l16;
                const int p = (quad + k2 * 4) ^ (row & 7);
                a[i] = *(const bf16x8*)(&As[row][p * 8]);
            }
#pragma unroll
            for (int j = 0; j < NJ; j++) {
                const int row = nw + j * 16 + l16;
                const int p = (quad + k2 * 4) ^ (row & 7);
                b[j] = *(const bf16x8*)(&Bs[row][p * 8]);
            }
#pragma unroll
            for (int i = 0; i < MI; i++)
#pragma unroll
                for (int j = 0; j < NJ; j++)
                    acc[i][j] = mfma32(a[i], b[j], acc[i][j]);
        }
        __syncthreads();
    }

    if (VSPLIT && n0 >= 2 * D_) {
        // V region: write transposed into vt[bh][hd][s], 4 consec s = 8B.
#pragma unroll
        for (int j = 0; j < NJ; j++) {
            const int gcol = n0 + nw + j * 16 + l16;
            const int col = gcol - 2 * D_;
            const int hh = col >> 6, hd = col & 63;
            const float bv = bias[gcol];
#pragma unroll
            for (int i = 0; i < MI; i++) {
                const int row = m0 + mw + i * 16 + quad * 4;
                const int bb = row >> 11, ss = row & 2047;
                unsigned long long pkv = 0;
#pragma unroll
                for (int r = 0; r < 4; r++)
                    pkv |= (unsigned long long)f2bf(acc[i][j][r] + bv) << (16 * r);
                *(unsigned long long*)(vt +
                    ((size_t)(bb * H_ + hh) * HD_ + hd) * S_ + ss) = pkv;
            }
        }
        return;
    }

#pragma unroll
    for (int j = 0; j < NJ; j++) {
        const int col = n0 + nw + j * 16 + l16;
        const float bv = bias[col];
#pragma unroll
        for (int i = 0; i < MI; i++) {
#pragma unroll
            for (int r = 0; r < 4; r++) {
                const int row = m0 + mw + i * 16 + quad * 4 + r;
                const float v = acc[i][j][r] + bv;
                if (OUT_F32) ((float*)Cp)[(size_t)row * N + col] = v;
                else         ((unsigned short*)Cp)[(size_t)row * N + col] = f2bf(v);
            }
        }
    }
}

// ---------------------------------------------------------------------------
// Flash attention — r32: UNSPLIT key loop (NT=32, one block per (qt,bh))
// with XCD-aware remap: id -> xcd=id&7, ix=id>>3, bh=xcd*3+(ix>>5),
// qt=ix&31 (bijective over 768). Each XCD owns 3 whole heads -> 1.5MB K+V
// L2-resident. K/V glds16-staged into swizzled LDS dbuf; unnormalized exp2
// softmax with Q-prescale; l on the MFMA pipe; in-register normalize;
// direct bf16 o write. No partials, no combine.
//
// Key-row permutation (r22, verified): A-frag row l16 of tile-slice nt reads
// Ks row rowp = (nt>>1)*32 + (l16>>2)*8 + (nt&1)*4 + (l16&3) =>
// s_acc[nt][r] = S[key=(nt>>1)*32+quad*8+(nt&1)*4+r][q=l16]; packed pa0/pa1
// are exactly the PV A-frags. Ks swizzle sK(row)=(row&3)|((row>>3&1)<<2);
// Vs swizzle g^(row&7); glds16 with pre-swizzled global source.
// l-ones: mfma(pa, ones) -> C rows match o_acc rows; l[r] lane-local.
// ---------------------------------------------------------------------------
__global__ __launch_bounds__(256) void attn_kernel(
    const unsigned short* __restrict__ qkv,  // [B*S][3*D] bf16
    const unsigned short* __restrict__ vt,   // [B*H][HD][S] bf16
    unsigned short* __restrict__ o)          // [B*S][D] bf16
{
    __shared__ __align__(16) unsigned short Ks[2][64][64];   // [key][hd], sK swizzle
    __shared__ __align__(16) unsigned short Vs[2][64][64];   // [hd][key], g^(row&7)

    const int t = threadIdx.x;
    const int w = t >> 6, lane = t & 63, quad = lane >> 4, l16 = lane & 15;
    const int h8 = l16 & 7;
    // XCD-aware decode (bijective over 768 blocks; 8 XCDs round-robin)
    const int id = blockIdx.x;
    const int xcd = id & 7, ix = id >> 3;
    const int bh = xcd * 3 + (ix >> 5);      // 0..23
    const int qt = ix & 31;
    const int b = bh / H_, h = bh % H_;
    const int ld = 3 * D_;  // 2304

    // Q B-frags (n=l16 -> q row, k=quad*8+j), prescaled by SCALE*log2e
    const unsigned short* qbase =
        qkv + (size_t)(b * S_ + qt * 64 + 16 * w + l16) * ld + h * HD_;
    u16x8 qr0 = *(const u16x8*)(qbase + quad * 8);
    u16x8 qr1 = *(const u16x8*)(qbase + 32 + quad * 8);
    bf16x8 qf0, qf1;
#pragma unroll
    for (int j = 0; j < 8; j++) {
        qf0[j] = (short)f2bf(bf2f(qr0[j]) * EXP2C_);
        qf1[j] = (short)f2bf(bf2f(qr1[j]) * EXP2C_);
    }

    bf16x8 ones;
#pragma unroll
    for (int j = 0; j < 8; j++) ones[j] = (short)0x3F80;  // bf16 1.0

    const unsigned short* kbase = qkv + (size_t)(b * S_) * ld + D_ + h * HD_;
    const unsigned short* vbase = vt + (size_t)bh * HD_ * S_;

    // per-lane staging source addresses (pre-swizzled global groups)
    const int c0 = t, c1 = t + 256;
    const int row0 = c0 >> 3, row1 = c1 >> 3;
    const int kg0 = (c0 & 7) ^ ((row0 & 3) | (((row0 >> 3) & 1) << 2));
    const int kg1 = (c1 & 7) ^ ((row1 & 3) | (((row1 >> 3) & 1) << 2));
    const int vg0 = (c0 & 7) ^ (row0 & 7);
    const int vg1 = (c1 & 7) ^ (row1 & 7);
    const unsigned short* kp0 = kbase + (size_t)row0 * ld + kg0 * 8;
    const unsigned short* kp1 = kbase + (size_t)row1 * ld + kg1 * 8;
    const unsigned short* vp0 = vbase + (size_t)row0 * S_ + vg0 * 8;
    const unsigned short* vp1 = vbase + (size_t)row1 * S_ + vg1 * 8;
    const size_t KSTEP = (size_t)64 * ld;  // elements per KV tile (K side)

    const f32x4 z = {0.f, 0.f, 0.f, 0.f};
    f32x4 o_acc[4] = {z, z, z, z};
    f32x4 l_acc = z;

    // prologue: stage tile 0 into buf 0
    glds16(kp0, &Ks[0][0][0] + c0 * 8);
    glds16(kp1, &Ks[0][0][0] + c1 * 8);
    glds16(vp0, &Vs[0][0][0] + c0 * 8);
    glds16(vp1, &Vs[0][0][0] + c1 * 8);
    kp0 += KSTEP; kp1 += KSTEP; vp0 += 64; vp1 += 64;
    __syncthreads();

    const int NT = S_ / 64;  // 32
    for (int kt = 0; kt < NT; kt++) {
        const int buf = kt & 1;

        // prefetch tile kt+1 into buf^1 (async, drains at the barrier)
        if (kt + 1 < NT) {
            unsigned short* kd = &Ks[buf ^ 1][0][0];
            unsigned short* vd = &Vs[buf ^ 1][0][0];
            glds16(kp0, kd + c0 * 8);
            glds16(kp1, kd + c1 * 8);
            glds16(vp0, vd + c0 * 8);
            glds16(vp1, vd + c1 * 8);
            kp0 += KSTEP; kp1 += KSTEP; vp0 += 64; vp1 += 64;
        }

        // S^T = K . Q^T from LDS: s_acc[nt][r] = S[key=perm(nt,quad*4+r)][q=l16]
        f32x4 s_acc[4] = {z, z, z, z};
#pragma unroll
        for (int nt = 0; nt < 4; nt++) {
            const int rowp = ((nt >> 1) << 5) + ((l16 >> 2) << 3) + ((nt & 1) << 2) + (l16 & 3);
            const int skr = (rowp & 3) | (((rowp >> 3) & 1) << 2);
            const unsigned short* kr = &Ks[buf][rowp][0];
            bf16x8 k0 = *(const bf16x8*)(kr + (quad ^ skr) * 8);
            bf16x8 k1 = *(const bf16x8*)(kr + ((quad ^ skr) ^ 4) * 8);
            s_acc[nt] = mfma32(k0, qf0, s_acc[nt]);
            s_acc[nt] = mfma32(k1, qf1, s_acc[nt]);
        }

        // V-frag reads issued early; lgkm latency hides under exp2/pack
        bf16x8 vr0[4], vr1[4];
#pragma unroll
        for (int nt = 0; nt < 4; nt++) {
            const int row = nt * 16 + l16;
            vr0[nt] = *(const bf16x8*)(&Vs[buf][row][(quad ^ h8) * 8]);
            vr1[nt] = *(const bf16x8*)(&Vs[buf][row][((quad ^ h8) ^ 4) * 8]);
        }

        // p = exp2(s); pack to PV A-frags in registers
        f32x4 pr[4];
#pragma unroll
        for (int nt = 0; nt < 4; nt++) {
#pragma unroll
            for (int r = 0; r < 4; r++) pr[nt][r] = fexp2(s_acc[nt][r]);
        }
        union { u32x4 u; bf16x8 h; } ca, cb;
        ca.u[0] = pk_bf16(pr[0][0], pr[0][1]);
        ca.u[1] = pk_bf16(pr[0][2], pr[0][3]);
        ca.u[2] = pk_bf16(pr[1][0], pr[1][1]);
        ca.u[3] = pk_bf16(pr[1][2], pr[1][3]);
        cb.u[0] = pk_bf16(pr[2][0], pr[2][1]);
        cb.u[1] = pk_bf16(pr[2][2], pr[2][3]);
        cb.u[2] = pk_bf16(pr[3][0], pr[3][1]);
        cb.u[3] = pk_bf16(pr[3][2], pr[3][3]);
        const bf16x8 pa0 = ca.h, pa1 = cb.h;

        // l on the MFMA pipe: C rows match o_acc rows, dup over cols
        l_acc = mfma32(pa0, ones, l_acc);
        l_acc = mfma32(pa1, ones, l_acc);

        // O += P . V from LDS (register V frags)
#pragma unroll
        for (int nt = 0; nt < 4; nt++) {
            o_acc[nt] = mfma32(pa0, vr0[nt], o_acc[nt]);
            o_acc[nt] = mfma32(pa1, vr1[nt], o_acc[nt]);
        }

        __syncthreads();  // drains glds16 (vmcnt) -> buf^1 complete
    }

    // epilogue: l[r] lane-local (dup over l16); normalize + direct bf16 write
#pragma unroll
    for (int r = 0; r < 4; r++) {
        const float inv = 1.f / l_acc[r];
        const int row = b * S_ + qt * 64 + 16 * w + quad * 4 + r;
        unsigned short* ob = o + (size_t)row * D_ + h * HD_;
#pragma unroll
        for (int nt = 0; nt < 4; nt++)
            ob[nt * 16 + l16] = f2bf(o_acc[nt][r] * inv);
    }
}

// ---------------------------------------------------------------------------
extern "C" void kernel_launch(void* const* d_in, const int* in_sizes, int n_in,
                              void* d_out, int out_size, void* d_ws, size_t ws_size,
                              hipStream_t stream) {
    const float* x      = (const float*)d_in[0];  // [4096][768]
    const float* w_qkv  = (const float*)d_in[1];  // [768][2304]
    const float* b_qkv  = (const float*)d_in[2];  // [2304]
    const float* w_proj = (const float*)d_in[3];  // [768][768]
    const float* b_proj = (const float*)d_in[4];  // [768]
    float* out = (float*)d_out;                   // [4096][768]

    // ws carve (bf16 elements). x16 ALIASES o: GEMM1 consumes x16 before
    // attn writes o (same stream, sequential).
    unsigned short* qkv    = (unsigned short*)d_ws;                     // 9,437,184
    unsigned short* vtb    = qkv    + (size_t)(B_ * S_) * (3 * D_);     // 3,145,728
    unsigned short* o_x16  = vtb    + (size_t)(B_ * H_) * HD_ * S_;     // 3,145,728
    unsigned short* wqkvT  = o_x16  + (size_t)(B_ * S_) * D_;           // 1,769,472
    unsigned short* wprojT = wqkvT  + (size_t)D_ * (3 * D_);            //   589,824

    dim3 blk(256);
    prep_kernel<<<dim3(PREP_CONV_ + PREP_TQKV_ + PREP_TPRJ_), blk, 0, stream>>>(
        x, o_x16, w_qkv, wqkvT, w_proj, wprojT);
    gemm_bt_kernel<128, 96, false, true><<<dim3((3 * D_) / 96, (B_ * S_) / 128), blk, 0, stream>>>(
        o_x16, wqkvT, b_qkv, qkv, vtb, B_ * S_, 3 * D_, D_);
    attn_kernel<<<dim3((S_ / 64) * (B_ * H_)), blk, 0, stream>>>(qkv, vtb, o_x16);
    gemm_bt_kernel<64, 64, true, false><<<dim3(D_ / 64, (B_ * S_) / 64), blk, 0, stream>>>(
        o_x16, wprojT, b_proj, out, nullptr, B_ * S_, D_, D_);
}

// Round 12
// 150.677 us; speedup vs baseline: 1.2589x; 1.0825x over previous
//
#include <hip/hip_runtime.h>
#include <hip/hip_bf16.h>

// Problem: B=2, S=2048, D=768, H=12, HD=64. fp32 in/out, bf16 MFMA inside.
// r33 = r32 (163.1us champion) + RAW v_exp_f32 for attn's exp2:
// __builtin_exp2f lowers to the extended-range sequence (~5-6 VALU insts:
// cmp/select/add/v_exp/scale-mul) unless approx-math is provable; with 16
// exp2/lane/iter that is the largest single VALU contributor (attn VALUBusy
// 58% vs MfmaUtil 19% - VALU is the loaded pipe). Inputs are bounded
// (|s|<~20; denormal p==0 vanishes in the sum) so bare v_exp_f32 via
// __builtin_amdgcn_exp2f is numerically sufficient.
// Win ledger: r4 LDS staging+dbuf, r5 xor-swizzle, r15 GEMM2 64x64,
// r18 GEMM1 128x96, r22 swapped-QK^T in-register P, r24 glds16 pre-swizzled
// staging + l-on-MFMA, r30 GEMM BK=64 swizzle, r31 XCD remap (FETCH 54->9MB)
// + repack_v folded into GEMM1 epilogue, r32 unsplit attn (combine deleted).
// Failure ledger (do not revisit): r7 mfma16, r8 wave-split, r11 32x32 MFMA,
// r12 attn BK=64, r9/r13/r14 math micro-opts, r16 GEMM1 64x128, r20 GEMM2
// dbuf, r23 2-wave/32q blocks, r25 V-direct-global mid-iter, r27 V-reg
// prefetch post-PV, r28 gemm2-fused combine, r29 cross-block combine
// (XCD non-coherent -> tripwire FAIL), r30 attn setprio (lockstep regime),
// r26/r31 split-k (combine tax > occupancy gain).
#define B_ 2
#define S_ 2048
#define D_ 768
#define H_ 12
#define HD_ 64
#define EXP2C_ 0.1803368801111244f  // SCALE * log2(e), folded into Q

typedef __attribute__((ext_vector_type(8))) short bf16x8;
typedef __attribute__((ext_vector_type(8))) unsigned short u16x8;
typedef __attribute__((ext_vector_type(4))) float f32x4;
typedef __attribute__((ext_vector_type(4))) unsigned int u32x4;

static __device__ __forceinline__ unsigned short f2bf(float x) {
    union { float f; unsigned u; } v; v.f = x;
    unsigned r = (v.u + 0x7FFFu + ((v.u >> 16) & 1u)) >> 16;  // RNE
    return (unsigned short)r;
}
static __device__ __forceinline__ float bf2f(unsigned short h) {
    union { unsigned u; float f; } v; v.u = ((unsigned)h) << 16;
    return v.f;
}
// bare hardware exp2 (v_exp_f32) — skips the extended-range fixup sequence.
// Inputs here are bounded; denormal-range outputs are ~0 and vanish in sums.
static __device__ __forceinline__ float fexp2(float x) {
#if __has_builtin(__builtin_amdgcn_exp2f)
    return __builtin_amdgcn_exp2f(x);
#else
    float r; asm("v_exp_f32 %0, %1" : "=v"(r) : "v"(x)); return r;
#endif
}

// packed f32x2 -> bf16x2 (v_cvt_pk_bf16_f32) as raw u32; low 16 = first arg
static __device__ __forceinline__ unsigned pk_bf16(float a, float b) {
    __hip_bfloat162 pk = __float22bfloat162_rn(make_float2(a, b));
    union { __hip_bfloat162 h; unsigned u; } v; v.h = pk;
    return v.u;
}

static __device__ __forceinline__ f32x4 mfma32(bf16x8 a, bf16x8 b, f32x4 c) {
    return __builtin_amdgcn_mfma_f32_16x16x32_bf16(a, b, c, 0, 0, 0);
}

// async global->LDS, 16B/lane; LDS dest = wave-uniform base + lane*16 (m97)
typedef __attribute__((address_space(3))) unsigned int lds_u32;
typedef __attribute__((address_space(1))) const unsigned int glb_u32;
static __device__ __forceinline__ void glds16(const unsigned short* g, unsigned short* l) {
    __builtin_amdgcn_global_load_lds((glb_u32*)g, (lds_u32*)l, 16, 0, 0);
}

// ---------------------------------------------------------------------------
// Merged prep: conv x->bf16 | transpose w_qkv | transpose w_proj.
// ---------------------------------------------------------------------------
#define PREP_CONV_ 1536   // 4096*768/(256*8)
#define PREP_TQKV_ 1728   // (2304/32)*(768/32)
#define PREP_TPRJ_ 576    // (768/32)*(768/32)
__global__ __launch_bounds__(256) void prep_kernel(
    const float* __restrict__ x,      unsigned short* __restrict__ x16,
    const float* __restrict__ w_qkv,  unsigned short* __restrict__ wqkvT,
    const float* __restrict__ w_proj, unsigned short* __restrict__ wprojT)
{
    __shared__ float tile[32][33];
    const int bid = blockIdx.x, t = threadIdx.x;
    if (bid < PREP_CONV_) {
        const int i = (bid * 256 + t) * 8;
        float4 a0 = *(const float4*)(x + i);
        float4 a1 = *(const float4*)(x + i + 4);
        u16x8 s;
        s[0] = f2bf(a0.x); s[1] = f2bf(a0.y); s[2] = f2bf(a0.z); s[3] = f2bf(a0.w);
        s[4] = f2bf(a1.x); s[5] = f2bf(a1.y); s[6] = f2bf(a1.z); s[7] = f2bf(a1.w);
        *(u16x8*)(x16 + i) = s;
        return;
    }
    const float* w; unsigned short* wT; int N, bb;
    if (bid < PREP_CONV_ + PREP_TQKV_) { w = w_qkv; wT = wqkvT; N = 3 * D_; bb = bid - PREP_CONV_; }
    else                               { w = w_proj; wT = wprojT; N = D_;   bb = bid - PREP_CONV_ - PREP_TQKV_; }
    const int K = D_;
    const int nt = N / 32;
    const int n0 = (bb % nt) * 32, k0 = (bb / nt) * 32;
    const int tx = t & 31, ty = t >> 5;
#pragma unroll
    for (int i = 0; i < 4; i++)
        tile[ty + i * 8][tx] = w[(size_t)(k0 + ty + i * 8) * N + n0 + tx];
    __syncthreads();
#pragma unroll
    for (int i = 0; i < 4; i++)
        wT[(size_t)(n0 + ty + i * 8) * K + k0 + tx] = f2bf(tile[tx][ty + i * 8]);
}

// ---------------------------------------------------------------------------
// Pure-bf16 GEMM + bias (r30 structure): BK=64 rows (128B = 8 x 16B groups),
// XOR-swizzled g^(row&7) on staging (pre-swizzled glds16 source, linear LDS
// dest) and frag reads ((quad+k2*4)^(row&7)) -> <=2-way (free).
// VSPLIT epilogue (r31): V-region blocks (n0 >= 2D) write C transposed
// directly into vt[bh][hd][s] (4 consecutive s per thread = one 8B store).
// ---------------------------------------------------------------------------
template <int BM, int BN, bool OUT_F32, bool VSPLIT>
__global__ __launch_bounds__(256) void gemm_bt_kernel(
    const unsigned short* __restrict__ A,
    const unsigned short* __restrict__ Bt,
    const float* __restrict__ bias,
    void* __restrict__ Cp,
    unsigned short* __restrict__ vt,   // VSPLIT target (else unused)
    int M, int N, int K)
{
    constexpr int BK = 64;
    __shared__ __align__(16) unsigned short As[BM][BK];
    __shared__ __align__(16) unsigned short Bs[BN][BK];
    constexpr int MI = BM / 32, NJ = BN / 32;     // frags per wave quadrant
    constexpr int ACH = BM * BK / 8;              // 16B chunks per A tile
    constexpr int BCH = BN * BK / 8;

    const int t = threadIdx.x;
    const int w = t >> 6, lane = t & 63, quad = lane >> 4, l16 = lane & 15;
    const int n0 = blockIdx.x * BN, m0 = blockIdx.y * BM;
    const int mw = (w & 1) * (BM / 2), nw = (w >> 1) * (BN / 2);

    const f32x4 z = {0.f, 0.f, 0.f, 0.f};
    f32x4 acc[MI][NJ];
#pragma unroll
    for (int i = 0; i < MI; i++)
#pragma unroll
        for (int j = 0; j < NJ; j++) acc[i][j] = z;

    for (int kk = 0; kk < K; kk += BK) {
#pragma unroll
        for (int it = 0; it < ACH / 256; it++) {
            const int c = t + it * 256;
            const int row = c >> 3, gs = (c & 7) ^ (row & 7);
            glds16(A + (size_t)(m0 + row) * K + kk + gs * 8, &As[0][0] + c * 8);
        }
#pragma unroll
        for (int it = 0; it < BCH / 256; it++) {
            const int c = t + it * 256;
            const int row = c >> 3, gs = (c & 7) ^ (row & 7);
            glds16(Bt + (size_t)(n0 + row) * K + kk + gs * 8, &Bs[0][0] + c * 8);
        }
        __syncthreads();

#pragma unroll
        for (int k2 = 0; k2 < 2; k2++) {
            bf16x8 a[MI], b[NJ];
#pragma unroll
            for (int i = 0; i < MI; i++) {
                const int row = mw + i * 16 + l16;
                const int p = (quad + k2 * 4) ^ (row & 7);
                a[i] = *(const bf16x8*)(&As[row][p * 8]);
            }
#pragma unroll
            for (int j = 0; j < NJ; j++) {
                const int row = nw + j * 16 + l16;
                const int p = (quad + k2 * 4) ^ (row & 7);
                b[j] = *(const bf16x8*)(&Bs[row][p * 8]);
            }
#pragma unroll
            for (int i = 0; i < MI; i++)
#pragma unroll
                for (int j = 0; j < NJ; j++)
                    acc[i][j] = mfma32(a[i], b[j], acc[i][j]);
        }
        __syncthreads();
    }

    if (VSPLIT && n0 >= 2 * D_) {
        // V region: write transposed into vt[bh][hd][s], 4 consec s = 8B.
#pragma unroll
        for (int j = 0; j < NJ; j++) {
            const int gcol = n0 + nw + j * 16 + l16;
            const int col = gcol - 2 * D_;
            const int hh = col >> 6, hd = col & 63;
            const float bv = bias[gcol];
#pragma unroll
            for (int i = 0; i < MI; i++) {
                const int row = m0 + mw + i * 16 + quad * 4;
                const int bb = row >> 11, ss = row & 2047;
                unsigned long long pkv = 0;
#pragma unroll
                for (int r = 0; r < 4; r++)
                    pkv |= (unsigned long long)f2bf(acc[i][j][r] + bv) << (16 * r);
                *(unsigned long long*)(vt +
                    ((size_t)(bb * H_ + hh) * HD_ + hd) * S_ + ss) = pkv;
            }
        }
        return;
    }

#pragma unroll
    for (int j = 0; j < NJ; j++) {
        const int col = n0 + nw + j * 16 + l16;
        const float bv = bias[col];
#pragma unroll
        for (int i = 0; i < MI; i++) {
#pragma unroll
            for (int r = 0; r < 4; r++) {
                const int row = m0 + mw + i * 16 + quad * 4 + r;
                const float v = acc[i][j][r] + bv;
                if (OUT_F32) ((float*)Cp)[(size_t)row * N + col] = v;
                else         ((unsigned short*)Cp)[(size_t)row * N + col] = f2bf(v);
            }
        }
    }
}

// ---------------------------------------------------------------------------
// Flash attention — r32 body (unsplit, XCD remap) with raw-v_exp_f32 exp2.
// id -> xcd=id&7, ix=id>>3, bh=xcd*3+(ix>>5), qt=ix&31 (bijective over 768).
// Each XCD owns 3 whole heads -> 1.5MB K+V L2-resident. K/V glds16-staged
// into swizzled LDS dbuf; unnormalized exp2 softmax with Q-prescale; l on
// the MFMA pipe; in-register normalize; direct bf16 o write.
//
// Key-row permutation (r22, verified): A-frag row l16 of tile-slice nt reads
// Ks row rowp = (nt>>1)*32 + (l16>>2)*8 + (nt&1)*4 + (l16&3) =>
// s_acc[nt][r] = S[key=(nt>>1)*32+quad*8+(nt&1)*4+r][q=l16]; packed pa0/pa1
// are exactly the PV A-frags. Ks swizzle sK(row)=(row&3)|((row>>3&1)<<2);
// Vs swizzle g^(row&7); glds16 with pre-swizzled global source.
// l-ones: mfma(pa, ones) -> C rows match o_acc rows; l[r] lane-local.
// ---------------------------------------------------------------------------
__global__ __launch_bounds__(256) void attn_kernel(
    const unsigned short* __restrict__ qkv,  // [B*S][3*D] bf16
    const unsigned short* __restrict__ vt,   // [B*H][HD][S] bf16
    unsigned short* __restrict__ o)          // [B*S][D] bf16
{
    __shared__ __align__(16) unsigned short Ks[2][64][64];   // [key][hd], sK swizzle
    __shared__ __align__(16) unsigned short Vs[2][64][64];   // [hd][key], g^(row&7)

    const int t = threadIdx.x;
    const int w = t >> 6, lane = t & 63, quad = lane >> 4, l16 = lane & 15;
    const int h8 = l16 & 7;
    // XCD-aware decode (bijective over 768 blocks; 8 XCDs round-robin)
    const int id = blockIdx.x;
    const int xcd = id & 7, ix = id >> 3;
    const int bh = xcd * 3 + (ix >> 5);      // 0..23
    const int qt = ix & 31;
    const int b = bh / H_, h = bh % H_;
    const int ld = 3 * D_;  // 2304

    // Q B-frags (n=l16 -> q row, k=quad*8+j), prescaled by SCALE*log2e
    const unsigned short* qbase =
        qkv + (size_t)(b * S_ + qt * 64 + 16 * w + l16) * ld + h * HD_;
    u16x8 qr0 = *(const u16x8*)(qbase + quad * 8);
    u16x8 qr1 = *(const u16x8*)(qbase + 32 + quad * 8);
    bf16x8 qf0, qf1;
#pragma unroll
    for (int j = 0; j < 8; j++) {
        qf0[j] = (short)f2bf(bf2f(qr0[j]) * EXP2C_);
        qf1[j] = (short)f2bf(bf2f(qr1[j]) * EXP2C_);
    }

    bf16x8 ones;
#pragma unroll
    for (int j = 0; j < 8; j++) ones[j] = (short)0x3F80;  // bf16 1.0

    const unsigned short* kbase = qkv + (size_t)(b * S_) * ld + D_ + h * HD_;
    const unsigned short* vbase = vt + (size_t)bh * HD_ * S_;

    // per-lane staging source addresses (pre-swizzled global groups)
    const int c0 = t, c1 = t + 256;
    const int row0 = c0 >> 3, row1 = c1 >> 3;
    const int kg0 = (c0 & 7) ^ ((row0 & 3) | (((row0 >> 3) & 1) << 2));
    const int kg1 = (c1 & 7) ^ ((row1 & 3) | (((row1 >> 3) & 1) << 2));
    const int vg0 = (c0 & 7) ^ (row0 & 7);
    const int vg1 = (c1 & 7) ^ (row1 & 7);
    const unsigned short* kp0 = kbase + (size_t)row0 * ld + kg0 * 8;
    const unsigned short* kp1 = kbase + (size_t)row1 * ld + kg1 * 8;
    const unsigned short* vp0 = vbase + (size_t)row0 * S_ + vg0 * 8;
    const unsigned short* vp1 = vbase + (size_t)row1 * S_ + vg1 * 8;
    const size_t KSTEP = (size_t)64 * ld;  // elements per KV tile (K side)

    const f32x4 z = {0.f, 0.f, 0.f, 0.f};
    f32x4 o_acc[4] = {z, z, z, z};
    f32x4 l_acc = z;

    // prologue: stage tile 0 into buf 0
    glds16(kp0, &Ks[0][0][0] + c0 * 8);
    glds16(kp1, &Ks[0][0][0] + c1 * 8);
    glds16(vp0, &Vs[0][0][0] + c0 * 8);
    glds16(vp1, &Vs[0][0][0] + c1 * 8);
    kp0 += KSTEP; kp1 += KSTEP; vp0 += 64; vp1 += 64;
    __syncthreads();

    const int NT = S_ / 64;  // 32
    for (int kt = 0; kt < NT; kt++) {
        const int buf = kt & 1;

        // prefetch tile kt+1 into buf^1 (async, drains at the barrier)
        if (kt + 1 < NT) {
            unsigned short* kd = &Ks[buf ^ 1][0][0];
            unsigned short* vd = &Vs[buf ^ 1][0][0];
            glds16(kp0, kd + c0 * 8);
            glds16(kp1, kd + c1 * 8);
            glds16(vp0, vd + c0 * 8);
            glds16(vp1, vd + c1 * 8);
            kp0 += KSTEP; kp1 += KSTEP; vp0 += 64; vp1 += 64;
        }

        // S^T = K . Q^T from LDS: s_acc[nt][r] = S[key=perm(nt,quad*4+r)][q=l16]
        f32x4 s_acc[4] = {z, z, z, z};
#pragma unroll
        for (int nt = 0; nt < 4; nt++) {
            const int rowp = ((nt >> 1) << 5) + ((l16 >> 2) << 3) + ((nt & 1) << 2) + (l16 & 3);
            const int skr = (rowp & 3) | (((rowp >> 3) & 1) << 2);
            const unsigned short* kr = &Ks[buf][rowp][0];
            bf16x8 k0 = *(const bf16x8*)(kr + (quad ^ skr) * 8);
            bf16x8 k1 = *(const bf16x8*)(kr + ((quad ^ skr) ^ 4) * 8);
            s_acc[nt] = mfma32(k0, qf0, s_acc[nt]);
            s_acc[nt] = mfma32(k1, qf1, s_acc[nt]);
        }

        // V-frag reads issued early; lgkm latency hides under exp2/pack
        bf16x8 vr0[4], vr1[4];
#pragma unroll
        for (int nt = 0; nt < 4; nt++) {
            const int row = nt * 16 + l16;
            vr0[nt] = *(const bf16x8*)(&Vs[buf][row][(quad ^ h8) * 8]);
            vr1[nt] = *(const bf16x8*)(&Vs[buf][row][((quad ^ h8) ^ 4) * 8]);
        }

        // p = exp2(s) via bare v_exp_f32; pack to PV A-frags in registers
        f32x4 pr[4];
#pragma unroll
        for (int nt = 0; nt < 4; nt++) {
#pragma unroll
            for (int r = 0; r < 4; r++) pr[nt][r] = fexp2(s_acc[nt][r]);
        }
        union { u32x4 u; bf16x8 h; } ca, cb;
        ca.u[0] = pk_bf16(pr[0][0], pr[0][1]);
        ca.u[1] = pk_bf16(pr[0][2], pr[0][3]);
        ca.u[2] = pk_bf16(pr[1][0], pr[1][1]);
        ca.u[3] = pk_bf16(pr[1][2], pr[1][3]);
        cb.u[0] = pk_bf16(pr[2][0], pr[2][1]);
        cb.u[1] = pk_bf16(pr[2][2], pr[2][3]);
        cb.u[2] = pk_bf16(pr[3][0], pr[3][1]);
        cb.u[3] = pk_bf16(pr[3][2], pr[3][3]);
        const bf16x8 pa0 = ca.h, pa1 = cb.h;

        // l on the MFMA pipe: C rows match o_acc rows, dup over cols
        l_acc = mfma32(pa0, ones, l_acc);
        l_acc = mfma32(pa1, ones, l_acc);

        // O += P . V from LDS (register V frags)
#pragma unroll
        for (int nt = 0; nt < 4; nt++) {
            o_acc[nt] = mfma32(pa0, vr0[nt], o_acc[nt]);
            o_acc[nt] = mfma32(pa1, vr1[nt], o_acc[nt]);
        }

        __syncthreads();  // drains glds16 (vmcnt) -> buf^1 complete
    }

    // epilogue: l[r] lane-local (dup over l16); normalize + direct bf16 write
#pragma unroll
    for (int r = 0; r < 4; r++) {
        const float inv = 1.f / l_acc[r];
        const int row = b * S_ + qt * 64 + 16 * w + quad * 4 + r;
        unsigned short* ob = o + (size_t)row * D_ + h * HD_;
#pragma unroll
        for (int nt = 0; nt < 4; nt++)
            ob[nt * 16 + l16] = f2bf(o_acc[nt][r] * inv);
    }
}

// ---------------------------------------------------------------------------
extern "C" void kernel_launch(void* const* d_in, const int* in_sizes, int n_in,
                              void* d_out, int out_size, void* d_ws, size_t ws_size,
                              hipStream_t stream) {
    const float* x      = (const float*)d_in[0];  // [4096][768]
    const float* w_qkv  = (const float*)d_in[1];  // [768][2304]
    const float* b_qkv  = (const float*)d_in[2];  // [2304]
    const float* w_proj = (const float*)d_in[3];  // [768][768]
    const float* b_proj = (const float*)d_in[4];  // [768]
    float* out = (float*)d_out;                   // [4096][768]

    // ws carve (bf16 elements). x16 ALIASES o: GEMM1 consumes x16 before
    // attn writes o (same stream, sequential).
    unsigned short* qkv    = (unsigned short*)d_ws;                     // 9,437,184
    unsigned short* vtb    = qkv    + (size_t)(B_ * S_) * (3 * D_);     // 3,145,728
    unsigned short* o_x16  = vtb    + (size_t)(B_ * H_) * HD_ * S_;     // 3,145,728
    unsigned short* wqkvT  = o_x16  + (size_t)(B_ * S_) * D_;           // 1,769,472
    unsigned short* wprojT = wqkvT  + (size_t)D_ * (3 * D_);            //   589,824

    dim3 blk(256);
    prep_kernel<<<dim3(PREP_CONV_ + PREP_TQKV_ + PREP_TPRJ_), blk, 0, stream>>>(
        x, o_x16, w_qkv, wqkvT, w_proj, wprojT);
    gemm_bt_kernel<128, 96, false, true><<<dim3((3 * D_) / 96, (B_ * S_) / 128), blk, 0, stream>>>(
        o_x16, wqkvT, b_qkv, qkv, vtb, B_ * S_, 3 * D_, D_);
    attn_kernel<<<dim3((S_ / 64) * (B_ * H_)), blk, 0, stream>>>(qkv, vtb, o_x16);
    gemm_bt_kernel<64, 64, true, false><<<dim3(D_ / 64, (B_ * S_) / 64), blk, 0, stream>>>(
        o_x16, wprojT, b_proj, out, nullptr, B_ * S_, D_, D_);
}

// Round 13
// 149.349 us; speedup vs baseline: 1.2701x; 1.0089x over previous
//
#include <hip/hip_runtime.h>
#include <hip/hip_bf16.h>

// Problem: B=2, S=2048, D=768, H=12, HD=64. fp32 in/out, bf16 MFMA inside.
// r34 = r33 (150.7us champion) + attn COUNTED-VMCNT 2-DEEP PIPELINE (T4):
// 3 LDS buffers (48KB, still 3 blk/CU), tile kt+2 staged at iter kt, and
// __syncthreads (which drains vmcnt(0), exposing the same-iter glds16
// L2 round-trip) replaced by s_waitcnt vmcnt(4) + raw s_barrier. The wait
// targets tile kt+1's loads, issued a FULL iteration (~3.5k cyc) earlier ->
// near-free. Tail iters use vmcnt(0). Safety: frag ds_reads are consumed by
// MFMA before the barrier (compiler lgkmcnt); each wave's vmcnt(4) ensures
// its tile-kt+1 stores landed; buffer (kt+2)%3 last read at iter kt-1.
// Win ledger: r4 LDS staging+dbuf, r5 xor-swizzle, r15 GEMM2 64x64,
// r18 GEMM1 128x96, r22 swapped-QK^T in-register P, r24 glds16 pre-swizzled
// staging + l-on-MFMA, r30 GEMM BK=64 swizzle, r31 XCD remap + repack fold,
// r32 unsplit attn, r33 raw v_exp_f32 (attn 60->47.8, VALUBusy 58->46).
// Failure ledger (do not revisit): r7 mfma16, r8 wave-split, r11 32x32 MFMA,
// r12 attn BK=64, r9/r13/r14 math micro-opts, r16 GEMM1 64x128, r20 GEMM2
// dbuf, r23 2-wave/32q blocks, r25 V-direct-global mid-iter, r27 V-reg
// prefetch post-PV, r28 gemm2-fused combine, r29 cross-block combine
// (XCD non-coherent -> tripwire FAIL), r30 attn setprio (lockstep regime),
// r26/r31 split-k (combine tax > occupancy gain).
#define B_ 2
#define S_ 2048
#define D_ 768
#define H_ 12
#define HD_ 64
#define EXP2C_ 0.1803368801111244f  // SCALE * log2(e), folded into Q

typedef __attribute__((ext_vector_type(8))) short bf16x8;
typedef __attribute__((ext_vector_type(8))) unsigned short u16x8;
typedef __attribute__((ext_vector_type(4))) float f32x4;
typedef __attribute__((ext_vector_type(4))) unsigned int u32x4;

static __device__ __forceinline__ unsigned short f2bf(float x) {
    union { float f; unsigned u; } v; v.f = x;
    unsigned r = (v.u + 0x7FFFu + ((v.u >> 16) & 1u)) >> 16;  // RNE
    return (unsigned short)r;
}
static __device__ __forceinline__ float bf2f(unsigned short h) {
    union { unsigned u; float f; } v; v.u = ((unsigned)h) << 16;
    return v.f;
}
// bare hardware exp2 (v_exp_f32) — r33 win. Inputs bounded; denormal p~=0.
static __device__ __forceinline__ float fexp2(float x) {
#if __has_builtin(__builtin_amdgcn_exp2f)
    return __builtin_amdgcn_exp2f(x);
#else
    float r; asm("v_exp_f32 %0, %1" : "=v"(r) : "v"(x)); return r;
#endif
}

// packed f32x2 -> bf16x2 (v_cvt_pk_bf16_f32) as raw u32; low 16 = first arg
static __device__ __forceinline__ unsigned pk_bf16(float a, float b) {
    __hip_bfloat162 pk = __float22bfloat162_rn(make_float2(a, b));
    union { __hip_bfloat162 h; unsigned u; } v; v.h = pk;
    return v.u;
}

static __device__ __forceinline__ f32x4 mfma32(bf16x8 a, bf16x8 b, f32x4 c) {
    return __builtin_amdgcn_mfma_f32_16x16x32_bf16(a, b, c, 0, 0, 0);
}

// async global->LDS, 16B/lane; LDS dest = wave-uniform base + lane*16 (m97)
typedef __attribute__((address_space(3))) unsigned int lds_u32;
typedef __attribute__((address_space(1))) const unsigned int glb_u32;
static __device__ __forceinline__ void glds16(const unsigned short* g, unsigned short* l) {
    __builtin_amdgcn_global_load_lds((glb_u32*)g, (lds_u32*)l, 16, 0, 0);
}

// ---------------------------------------------------------------------------
// Merged prep: conv x->bf16 | transpose w_qkv | transpose w_proj.
// ---------------------------------------------------------------------------
#define PREP_CONV_ 1536   // 4096*768/(256*8)
#define PREP_TQKV_ 1728   // (2304/32)*(768/32)
#define PREP_TPRJ_ 576    // (768/32)*(768/32)
__global__ __launch_bounds__(256) void prep_kernel(
    const float* __restrict__ x,      unsigned short* __restrict__ x16,
    const float* __restrict__ w_qkv,  unsigned short* __restrict__ wqkvT,
    const float* __restrict__ w_proj, unsigned short* __restrict__ wprojT)
{
    __shared__ float tile[32][33];
    const int bid = blockIdx.x, t = threadIdx.x;
    if (bid < PREP_CONV_) {
        const int i = (bid * 256 + t) * 8;
        float4 a0 = *(const float4*)(x + i);
        float4 a1 = *(const float4*)(x + i + 4);
        u16x8 s;
        s[0] = f2bf(a0.x); s[1] = f2bf(a0.y); s[2] = f2bf(a0.z); s[3] = f2bf(a0.w);
        s[4] = f2bf(a1.x); s[5] = f2bf(a1.y); s[6] = f2bf(a1.z); s[7] = f2bf(a1.w);
        *(u16x8*)(x16 + i) = s;
        return;
    }
    const float* w; unsigned short* wT; int N, bb;
    if (bid < PREP_CONV_ + PREP_TQKV_) { w = w_qkv; wT = wqkvT; N = 3 * D_; bb = bid - PREP_CONV_; }
    else                               { w = w_proj; wT = wprojT; N = D_;   bb = bid - PREP_CONV_ - PREP_TQKV_; }
    const int K = D_;
    const int nt = N / 32;
    const int n0 = (bb % nt) * 32, k0 = (bb / nt) * 32;
    const int tx = t & 31, ty = t >> 5;
#pragma unroll
    for (int i = 0; i < 4; i++)
        tile[ty + i * 8][tx] = w[(size_t)(k0 + ty + i * 8) * N + n0 + tx];
    __syncthreads();
#pragma unroll
    for (int i = 0; i < 4; i++)
        wT[(size_t)(n0 + ty + i * 8) * K + k0 + tx] = f2bf(tile[tx][ty + i * 8]);
}

// ---------------------------------------------------------------------------
// Pure-bf16 GEMM + bias (r30 structure): BK=64 rows (128B = 8 x 16B groups),
// XOR-swizzled g^(row&7) on staging (pre-swizzled glds16 source, linear LDS
// dest) and frag reads ((quad+k2*4)^(row&7)) -> <=2-way (free).
// VSPLIT epilogue (r31): V-region blocks (n0 >= 2D) write C transposed
// directly into vt[bh][hd][s] (4 consecutive s per thread = one 8B store).
// ---------------------------------------------------------------------------
template <int BM, int BN, bool OUT_F32, bool VSPLIT>
__global__ __launch_bounds__(256) void gemm_bt_kernel(
    const unsigned short* __restrict__ A,
    const unsigned short* __restrict__ Bt,
    const float* __restrict__ bias,
    void* __restrict__ Cp,
    unsigned short* __restrict__ vt,   // VSPLIT target (else unused)
    int M, int N, int K)
{
    constexpr int BK = 64;
    __shared__ __align__(16) unsigned short As[BM][BK];
    __shared__ __align__(16) unsigned short Bs[BN][BK];
    constexpr int MI = BM / 32, NJ = BN / 32;     // frags per wave quadrant
    constexpr int ACH = BM * BK / 8;              // 16B chunks per A tile
    constexpr int BCH = BN * BK / 8;

    const int t = threadIdx.x;
    const int w = t >> 6, lane = t & 63, quad = lane >> 4, l16 = lane & 15;
    const int n0 = blockIdx.x * BN, m0 = blockIdx.y * BM;
    const int mw = (w & 1) * (BM / 2), nw = (w >> 1) * (BN / 2);

    const f32x4 z = {0.f, 0.f, 0.f, 0.f};
    f32x4 acc[MI][NJ];
#pragma unroll
    for (int i = 0; i < MI; i++)
#pragma unroll
        for (int j = 0; j < NJ; j++) acc[i][j] = z;

    for (int kk = 0; kk < K; kk += BK) {
#pragma unroll
        for (int it = 0; it < ACH / 256; it++) {
            const int c = t + it * 256;
            const int row = c >> 3, gs = (c & 7) ^ (row & 7);
            glds16(A + (size_t)(m0 + row) * K + kk + gs * 8, &As[0][0] + c * 8);
        }
#pragma unroll
        for (int it = 0; it < BCH / 256; it++) {
            const int c = t + it * 256;
            const int row = c >> 3, gs = (c & 7) ^ (row & 7);
            glds16(Bt + (size_t)(n0 + row) * K + kk + gs * 8, &Bs[0][0] + c * 8);
        }
        __syncthreads();

#pragma unroll
        for (int k2 = 0; k2 < 2; k2++) {
            bf16x8 a[MI], b[NJ];
#pragma unroll
            for (int i = 0; i < MI; i++) {
                const int row = mw + i * 16 + l16;
                const int p = (quad + k2 * 4) ^ (row & 7);
                a[i] = *(const bf16x8*)(&As[row][p * 8]);
            }
#pragma unroll
            for (int j = 0; j < NJ; j++) {
                const int row = nw + j * 16 + l16;
                const int p = (quad + k2 * 4) ^ (row & 7);
                b[j] = *(const bf16x8*)(&Bs[row][p * 8]);
            }
#pragma unroll
            for (int i = 0; i < MI; i++)
#pragma unroll
                for (int j = 0; j < NJ; j++)
                    acc[i][j] = mfma32(a[i], b[j], acc[i][j]);
        }
        __syncthreads();
    }

    if (VSPLIT && n0 >= 2 * D_) {
        // V region: write transposed into vt[bh][hd][s], 4 consec s = 8B.
#pragma unroll
        for (int j = 0; j < NJ; j++) {
            const int gcol = n0 + nw + j * 16 + l16;
            const int col = gcol - 2 * D_;
            const int hh = col >> 6, hd = col & 63;
            const float bv = bias[gcol];
#pragma unroll
            for (int i = 0; i < MI; i++) {
                const int row = m0 + mw + i * 16 + quad * 4;
                const int bb = row >> 11, ss = row & 2047;
                unsigned long long pkv = 0;
#pragma unroll
                for (int r = 0; r < 4; r++)
                    pkv |= (unsigned long long)f2bf(acc[i][j][r] + bv) << (16 * r);
                *(unsigned long long*)(vt +
                    ((size_t)(bb * H_ + hh) * HD_ + hd) * S_ + ss) = pkv;
            }
        }
        return;
    }

#pragma unroll
    for (int j = 0; j < NJ; j++) {
        const int col = n0 + nw + j * 16 + l16;
        const float bv = bias[col];
#pragma unroll
        for (int i = 0; i < MI; i++) {
#pragma unroll
            for (int r = 0; r < 4; r++) {
                const int row = m0 + mw + i * 16 + quad * 4 + r;
                const float v = acc[i][j][r] + bv;
                if (OUT_F32) ((float*)Cp)[(size_t)row * N + col] = v;
                else         ((unsigned short*)Cp)[(size_t)row * N + col] = f2bf(v);
            }
        }
    }
}

// ---------------------------------------------------------------------------
// Flash attention — r34: r33 body (unsplit, XCD remap, raw v_exp) with
// 3-buffer 2-deep counted-vmcnt pipeline. Per iter: stage tile kt+2 into
// buf (kt+2)%3; compute tile kt from buf kt%3; s_waitcnt vmcnt(4) (tile
// kt+1's 4 loads done, tile kt+2's 4 stay in flight) + raw s_barrier.
// Tail (kt+2>=NT): vmcnt(0).
//
// Key-row permutation (r22, verified): A-frag row l16 of tile-slice nt reads
// Ks row rowp = (nt>>1)*32 + (l16>>2)*8 + (nt&1)*4 + (l16&3) =>
// s_acc[nt][r] = S[key=(nt>>1)*32+quad*8+(nt&1)*4+r][q=l16]; packed pa0/pa1
// are exactly the PV A-frags. Ks swizzle sK(row)=(row&3)|((row>>3&1)<<2);
// Vs swizzle g^(row&7); glds16 with pre-swizzled global source.
// l-ones: mfma(pa, ones) -> C rows match o_acc rows; l[r] lane-local.
// ---------------------------------------------------------------------------
__global__ __launch_bounds__(256) void attn_kernel(
    const unsigned short* __restrict__ qkv,  // [B*S][3*D] bf16
    const unsigned short* __restrict__ vt,   // [B*H][HD][S] bf16
    unsigned short* __restrict__ o)          // [B*S][D] bf16
{
    __shared__ __align__(16) unsigned short Ks[3][64][64];   // [key][hd], sK swizzle
    __shared__ __align__(16) unsigned short Vs[3][64][64];   // [hd][key], g^(row&7)

    const int t = threadIdx.x;
    const int w = t >> 6, lane = t & 63, quad = lane >> 4, l16 = lane & 15;
    const int h8 = l16 & 7;
    // XCD-aware decode (bijective over 768 blocks; 8 XCDs round-robin)
    const int id = blockIdx.x;
    const int xcd = id & 7, ix = id >> 3;
    const int bh = xcd * 3 + (ix >> 5);      // 0..23
    const int qt = ix & 31;
    const int b = bh / H_, h = bh % H_;
    const int ld = 3 * D_;  // 2304

    // Q B-frags (n=l16 -> q row, k=quad*8+j), prescaled by SCALE*log2e
    const unsigned short* qbase =
        qkv + (size_t)(b * S_ + qt * 64 + 16 * w + l16) * ld + h * HD_;
    u16x8 qr0 = *(const u16x8*)(qbase + quad * 8);
    u16x8 qr1 = *(const u16x8*)(qbase + 32 + quad * 8);
    bf16x8 qf0, qf1;
#pragma unroll
    for (int j = 0; j < 8; j++) {
        qf0[j] = (short)f2bf(bf2f(qr0[j]) * EXP2C_);
        qf1[j] = (short)f2bf(bf2f(qr1[j]) * EXP2C_);
    }

    bf16x8 ones;
#pragma unroll
    for (int j = 0; j < 8; j++) ones[j] = (short)0x3F80;  // bf16 1.0

    const unsigned short* kbase = qkv + (size_t)(b * S_) * ld + D_ + h * HD_;
    const unsigned short* vbase = vt + (size_t)bh * HD_ * S_;

    // per-lane staging source addresses (pre-swizzled global groups)
    const int c0 = t, c1 = t + 256;
    const int row0 = c0 >> 3, row1 = c1 >> 3;
    const int kg0 = (c0 & 7) ^ ((row0 & 3) | (((row0 >> 3) & 1) << 2));
    const int kg1 = (c1 & 7) ^ ((row1 & 3) | (((row1 >> 3) & 1) << 2));
    const int vg0 = (c0 & 7) ^ (row0 & 7);
    const int vg1 = (c1 & 7) ^ (row1 & 7);
    const unsigned short* kp0 = kbase + (size_t)row0 * ld + kg0 * 8;
    const unsigned short* kp1 = kbase + (size_t)row1 * ld + kg1 * 8;
    const unsigned short* vp0 = vbase + (size_t)row0 * S_ + vg0 * 8;
    const unsigned short* vp1 = vbase + (size_t)row1 * S_ + vg1 * 8;
    const size_t KSTEP = (size_t)64 * ld;  // elements per KV tile (K side)

    const f32x4 z = {0.f, 0.f, 0.f, 0.f};
    f32x4 o_acc[4] = {z, z, z, z};
    f32x4 l_acc = z;

    // prologue: stage tiles 0 and 1 into bufs 0 and 1 (8 loads in flight)
#pragma unroll
    for (int pt = 0; pt < 2; pt++) {
        glds16(kp0, &Ks[pt][0][0] + c0 * 8);
        glds16(kp1, &Ks[pt][0][0] + c1 * 8);
        glds16(vp0, &Vs[pt][0][0] + c0 * 8);
        glds16(vp1, &Vs[pt][0][0] + c1 * 8);
        kp0 += KSTEP; kp1 += KSTEP; vp0 += 64; vp1 += 64;
    }
    asm volatile("s_waitcnt vmcnt(4)" ::: "memory");  // tile 0 landed
    __builtin_amdgcn_s_barrier();

    const int NT = S_ / 64;  // 32
    int bc = 0;              // buffer holding tile kt
    for (int kt = 0; kt < NT; kt++) {
        const bool pre = (kt + 2 < NT);

        // stage tile kt+2 into buf (bc+2)%3 (async; stays in flight past
        // this iter's barrier — only tile kt+1's loads are waited on)
        if (pre) {
            const int bp = (bc + 2 >= 3) ? bc - 1 : bc + 2;
            unsigned short* kd = &Ks[bp][0][0];
            unsigned short* vd = &Vs[bp][0][0];
            glds16(kp0, kd + c0 * 8);
            glds16(kp1, kd + c1 * 8);
            glds16(vp0, vd + c0 * 8);
            glds16(vp1, vd + c1 * 8);
            kp0 += KSTEP; kp1 += KSTEP; vp0 += 64; vp1 += 64;
        }

        // S^T = K . Q^T from LDS: s_acc[nt][r] = S[key=perm(nt,quad*4+r)][q=l16]
        f32x4 s_acc[4] = {z, z, z, z};
#pragma unroll
        for (int nt = 0; nt < 4; nt++) {
            const int rowp = ((nt >> 1) << 5) + ((l16 >> 2) << 3) + ((nt & 1) << 2) + (l16 & 3);
            const int skr = (rowp & 3) | (((rowp >> 3) & 1) << 2);
            const unsigned short* kr = &Ks[bc][rowp][0];
            bf16x8 k0 = *(const bf16x8*)(kr + (quad ^ skr) * 8);
            bf16x8 k1 = *(const bf16x8*)(kr + ((quad ^ skr) ^ 4) * 8);
            s_acc[nt] = mfma32(k0, qf0, s_acc[nt]);
            s_acc[nt] = mfma32(k1, qf1, s_acc[nt]);
        }

        // V-frag reads issued early; lgkm latency hides under exp2/pack
        bf16x8 vr0[4], vr1[4];
#pragma unroll
        for (int nt = 0; nt < 4; nt++) {
            const int row = nt * 16 + l16;
            vr0[nt] = *(const bf16x8*)(&Vs[bc][row][(quad ^ h8) * 8]);
            vr1[nt] = *(const bf16x8*)(&Vs[bc][row][((quad ^ h8) ^ 4) * 8]);
        }

        // p = exp2(s) via bare v_exp_f32; pack to PV A-frags in registers
        f32x4 pr[4];
#pragma unroll
        for (int nt = 0; nt < 4; nt++) {
#pragma unroll
            for (int r = 0; r < 4; r++) pr[nt][r] = fexp2(s_acc[nt][r]);
        }
        union { u32x4 u; bf16x8 h; } ca, cb;
        ca.u[0] = pk_bf16(pr[0][0], pr[0][1]);
        ca.u[1] = pk_bf16(pr[0][2], pr[0][3]);
        ca.u[2] = pk_bf16(pr[1][0], pr[1][1]);
        ca.u[3] = pk_bf16(pr[1][2], pr[1][3]);
        cb.u[0] = pk_bf16(pr[2][0], pr[2][1]);
        cb.u[1] = pk_bf16(pr[2][2], pr[2][3]);
        cb.u[2] = pk_bf16(pr[3][0], pr[3][1]);
        cb.u[3] = pk_bf16(pr[3][2], pr[3][3]);
        const bf16x8 pa0 = ca.h, pa1 = cb.h;

        // l on the MFMA pipe: C rows match o_acc rows, dup over cols
        l_acc = mfma32(pa0, ones, l_acc);
        l_acc = mfma32(pa1, ones, l_acc);

        // O += P . V from LDS (register V frags)
#pragma unroll
        for (int nt = 0; nt < 4; nt++) {
            o_acc[nt] = mfma32(pa0, vr0[nt], o_acc[nt]);
            o_acc[nt] = mfma32(pa1, vr1[nt], o_acc[nt]);
        }

        // counted vmcnt: require tile kt+1 landed; tile kt+2 stays in flight
        if (pre) asm volatile("s_waitcnt vmcnt(4)" ::: "memory");
        else     asm volatile("s_waitcnt vmcnt(0)" ::: "memory");
        __builtin_amdgcn_s_barrier();
        bc = (bc + 1 == 3) ? 0 : bc + 1;
    }

    // epilogue: l[r] lane-local (dup over l16); normalize + direct bf16 write
#pragma unroll
    for (int r = 0; r < 4; r++) {
        const float inv = 1.f / l_acc[r];
        const int row = b * S_ + qt * 64 + 16 * w + quad * 4 + r;
        unsigned short* ob = o + (size_t)row * D_ + h * HD_;
#pragma unroll
        for (int nt = 0; nt < 4; nt++)
            ob[nt * 16 + l16] = f2bf(o_acc[nt][r] * inv);
    }
}

// ---------------------------------------------------------------------------
extern "C" void kernel_launch(void* const* d_in, const int* in_sizes, int n_in,
                              void* d_out, int out_size, void* d_ws, size_t ws_size,
                              hipStream_t stream) {
    const float* x      = (const float*)d_in[0];  // [4096][768]
    const float* w_qkv  = (const float*)d_in[1];  // [768][2304]
    const float* b_qkv  = (const float*)d_in[2];  // [2304]
    const float* w_proj = (const float*)d_in[3];  // [768][768]
    const float* b_proj = (const float*)d_in[4];  // [768]
    float* out = (float*)d_out;                   // [4096][768]

    // ws carve (bf16 elements). x16 ALIASES o: GEMM1 consumes x16 before
    // attn writes o (same stream, sequential).
    unsigned short* qkv    = (unsigned short*)d_ws;                     // 9,437,184
    unsigned short* vtb    = qkv    + (size_t)(B_ * S_) * (3 * D_);     // 3,145,728
    unsigned short* o_x16  = vtb    + (size_t)(B_ * H_) * HD_ * S_;     // 3,145,728
    unsigned short* wqkvT  = o_x16  + (size_t)(B_ * S_) * D_;           // 1,769,472
    unsigned short* wprojT = wqkvT  + (size_t)D_ * (3 * D_);            //   589,824

    dim3 blk(256);
    prep_kernel<<<dim3(PREP_CONV_ + PREP_TQKV_ + PREP_TPRJ_), blk, 0, stream>>>(
        x, o_x16, w_qkv, wqkvT, w_proj, wprojT);
    gemm_bt_kernel<128, 96, false, true><<<dim3((3 * D_) / 96, (B_ * S_) / 128), blk, 0, stream>>>(
        o_x16, wqkvT, b_qkv, qkv, vtb, B_ * S_, 3 * D_, D_);
    attn_kernel<<<dim3((S_ / 64) * (B_ * H_)), blk, 0, stream>>>(qkv, vtb, o_x16);
    gemm_bt_kernel<64, 64, true, false><<<dim3(D_ / 64, (B_ * S_) / 64), blk, 0, stream>>>(
        o_x16, wprojT, b_proj, out, nullptr, B_ * S_, D_, D_);
}